// Round 10
// baseline (187.924 us; speedup 1.0000x reference)
//
#include <hip/hip_runtime.h>
#include <hip/hip_bf16.h>

#define DEV __device__ __forceinline__
#define AS1 __attribute__((address_space(1)))
#define AS3 __attribute__((address_space(3)))

typedef __attribute__((ext_vector_type(8))) short bf16x8;
typedef __attribute__((ext_vector_type(4))) float f32x4;

static constexpr int NR   = 16384;
static constexpr int DIN  = 512;
static constexpr int DHID = 2048;
static constexpr int DOUT = 512;
static constexpr int LR   = 64;          // 4 bands * rank 16
static constexpr int K1   = DIN + LR;    // 576
static constexpr int K2   = DHID + LR;   // 2112

DEV unsigned short f2bf(float f) {
  unsigned u = __float_as_uint(f);
  u += 0x7fffu + ((u >> 16) & 1u);
  return (unsigned short)(u >> 16);
}

// fast GELU: tanh-form, |err vs erf-form| < ~1.5e-3 (well under bf16 quantum of h)
DEV float fast_gelu(float v) {
  float x2 = v * v;
  float a  = -v * __builtin_fmaf(0.10294324f, x2, 2.30220817f);
  float t  = exp2f(a);
  return v * __builtin_amdgcn_rcpf(1.0f + t);
}

template<int N> DEV void wvm() {
  asm volatile("s_waitcnt vmcnt(%0)" :: "i"(N) : "memory");
}

// ---- x fp32 -> bf16 into xaug[:, 0:512] (row stride K1) ----
__global__ __launch_bounds__(256) void cvt_x_kernel(const float* __restrict__ x,
                                                    unsigned short* __restrict__ xaug) {
  int i = blockIdx.x * 256 + threadIdx.x;   // one float4 per thread
  if (i >= NR * DIN / 4) return;
  int e = i * 4;
  int r = e >> 9, c = e & 511;
  float4 v = ((const float4*)x)[i];
  uint2 o;
  o.x = (unsigned)f2bf(v.x) | ((unsigned)f2bf(v.y) << 16);
  o.y = (unsigned)f2bf(v.z) | ((unsigned)f2bf(v.w) << 16);
  *(uint2*)(xaug + (size_t)r * K1 + c) = o;
}

// ---- generic transpose+convert: in fp32 [R][C] -> out bf16 [C][LDO] at col offset CO ----
template<int R, int C, int LDO, int CO>
__global__ __launch_bounds__(256) void tconv_kernel(const float* __restrict__ in,
                                                    unsigned short* __restrict__ out) {
  __shared__ float t[32][33];
  int bc = blockIdx.x * 32, br = blockIdx.y * 32;
  int tx = threadIdx.x & 31, ty = threadIdx.x >> 5;   // ty 0..7
  #pragma unroll
  for (int i = 0; i < 32; i += 8)
    t[ty + i][tx] = in[(size_t)(br + ty + i) * C + bc + tx];
  __syncthreads();
  #pragma unroll
  for (int i = 0; i < 32; i += 8)
    out[(size_t)(bc + ty + i) * LDO + CO + br + tx] = f2bf(t[tx][ty + i]);
}

// ---- LoRA A rearrange: A [4][D][16] fp32 -> AT [64][D] bf16 ----
__global__ __launch_bounds__(256) void rearrA_kernel(const float* __restrict__ A,
                                                     unsigned short* __restrict__ AT, int D) {
  int tid = blockIdx.x * 256 + threadIdx.x;
  if (tid >= 64 * D) return;
  int j = tid / D, i = tid - j * D;
  AT[tid] = f2bf(A[((size_t)(j >> 4) * D + i) * 16 + (j & 15)]);
}

// ========== m97-regime GEMM: single-buffer, 2 barriers/tile, TLP occupancy ==========
// 4 waves (2x2), BK=64, LDS = (BM+BN)*64*2 bytes single-buffered -> 3-5 blocks/CU.
// Latency hiding comes from MULTIPLE RESIDENT BLOCKS, not intra-block pipelining.
// T2 swizzle (verified 0-conflict): source chunk XOR (row&7), same XOR on ds_read.
// A: [M][lda] bf16 K-contig. B: [BN panel][ldb] bf16 K-contig (weight^T).
// EPI: 0 = gelu(acc+bias)->bf16 out ; 1 = acc+bias->fp32 out
template<int BM, int BN, int WM, int WN, int K, int EPI>
__global__ __launch_bounds__(256) void gemm97_kernel(
    const unsigned short* __restrict__ A, int lda,
    const unsigned short* __restrict__ B, int ldb,
    const float* __restrict__ bias,
    void* __restrict__ outp, int ldo, int ocol) {
  constexpr int NT   = K / 64;
  constexpr int AISS = BM / 32;          // gload_lds per thread for A per tile
  constexpr int BISS = BN / 32;
  constexpr int WRM  = WM / 16, WRN = WN / 16;
  static_assert((BM / WM) * (BN / WN) == 4, "4 waves");
  __shared__ __align__(16) unsigned short lA[BM * 64];
  __shared__ __align__(16) unsigned short lB[BN * 64];

  const int tid  = threadIdx.x;
  const int w    = tid >> 6, lane = tid & 63;
  const int wr   = w >> 1, wc = w & 1;          // 2x2 wave grid
  const int bm   = blockIdx.x * BM, bn = blockIdx.y * BN;
  const int l15  = lane & 15;
  const int srow = lane >> 3;                   // staging row within 8-row group
  const int kc0  = ((lane >> 4) ^ (lane & 7)) * 8;        // kk=0 chunk (swizzled)
  const int kc1  = (((lane >> 4) + 4) ^ (lane & 7)) * 8;  // kk=1 chunk

  f32x4 acc[WRM][WRN] = {};

  for (int t = 0; t < NT; ++t) {
    // ---- stage tile t (single buffer) ----
    #pragma unroll
    for (int i = 0; i < AISS; ++i) {
      int row = i * 32 + w * 8 + srow;
      __builtin_amdgcn_global_load_lds(
          (const AS1 void*)(A + (size_t)(bm + row) * lda + (size_t)t * 64
                              + (((lane & 7) ^ (row & 7)) * 8)),
          (AS3 void*)(lA + (i * 32 + w * 8) * 64 + lane * 8), 16, 0, 0);
    }
    #pragma unroll
    for (int i = 0; i < BISS; ++i) {
      int row = i * 32 + w * 8 + srow;
      __builtin_amdgcn_global_load_lds(
          (const AS1 void*)(B + (size_t)(bn + row) * ldb + (size_t)t * 64
                              + (((lane & 7) ^ (row & 7)) * 8)),
          (AS3 void*)(lB + (i * 32 + w * 8) * 64 + lane * 8), 16, 0, 0);
    }
    __syncthreads();                     // drains vmcnt; tile visible

    // ---- compute ----
    bf16x8 af[WRM][2], bfv[WRN][2];
    #pragma unroll
    for (int m = 0; m < WRM; ++m) {
      int ro = (wr * WM + m * 16 + l15) * 64;
      af[m][0] = *(const bf16x8*)(lA + ro + kc0);
      af[m][1] = *(const bf16x8*)(lA + ro + kc1);
    }
    #pragma unroll
    for (int n = 0; n < WRN; ++n) {
      int ro = (wc * WN + n * 16 + l15) * 64;
      bfv[n][0] = *(const bf16x8*)(lB + ro + kc0);
      bfv[n][1] = *(const bf16x8*)(lB + ro + kc1);
    }
    #pragma unroll
    for (int m = 0; m < WRM; ++m)
      #pragma unroll
      for (int n = 0; n < WRN; ++n) {
        acc[m][n] = __builtin_amdgcn_mfma_f32_16x16x32_bf16(af[m][0], bfv[n][0], acc[m][n], 0, 0, 0);
        acc[m][n] = __builtin_amdgcn_mfma_f32_16x16x32_bf16(af[m][1], bfv[n][1], acc[m][n], 0, 0, 0);
      }
    __syncthreads();                     // all reads done before next stage
  }

  // epilogue: C/D layout col=lane&15, row=(lane>>4)*4+reg (verified m89/m91)
  const int r0 = bm + wr * WM;
  const int c0 = bn + wc * WN;
  float biasv[WRN];
  #pragma unroll
  for (int n = 0; n < WRN; ++n)
    biasv[n] = bias[c0 + n * 16 + l15];

  #pragma unroll
  for (int m = 0; m < WRM; ++m)
    #pragma unroll
    for (int n = 0; n < WRN; ++n) {
      int col  = c0 + n * 16 + l15;
      int rowb = r0 + m * 16 + ((lane >> 4) << 2);
      #pragma unroll
      for (int r = 0; r < 4; ++r) {
        float v = acc[m][n][r];
        int row = rowb + r;
        if (EPI == 0) {
          v = fast_gelu(v + biasv[n]);
          ((unsigned short*)outp)[(size_t)row * ldo + ocol + col] = f2bf(v);
        } else {
          v += biasv[n];
          ((float*)outp)[(size_t)row * ldo + col] = v;
        }
      }
    }
}

// ============ small GEMM for LoRA u-projections: BK=64, 3-buffer counted ring ============
// EPI2: acc*2*bw[row][col>>4] -> bf16 out at col offset
template<int BM, int BN, int WM, int WN, int K>
__global__ __launch_bounds__(256) void gemmu_kernel(
    const unsigned short* __restrict__ A, int lda,
    const unsigned short* __restrict__ B, int ldb,
    const float* __restrict__ bw,
    unsigned short* __restrict__ outp, int ldo, int ocol) {
  constexpr int WRM = WM / 16, WRN = WN / 16;
  constexpr int NWN = BN / WN;
  constexpr int NT  = K / 64;
  constexpr int NBUF = 3;
  constexpr int AISS = BM * 64 * 2 / 4096;   // gload_lds/thread for A per tile (=2)
  constexpr int BISS = BN * 64 * 2 / 4096;
  constexpr int LOADS = AISS + BISS;
  static_assert((BM / WM) * (BN / WN) == 4 && NT >= NBUF, "geometry");
  __shared__ __align__(16) unsigned short lA[NBUF * BM * 64];
  __shared__ __align__(16) unsigned short lB[NBUF * BN * 64];

  const int tid  = threadIdx.x;
  const int wid  = tid >> 6, lane = tid & 63;
  const int wr   = wid / NWN, wc = wid % NWN;
  const int bm   = blockIdx.x * BM, bn = blockIdx.y * BN;
  const int l15  = lane & 15;
  const int kc0  = ((lane >> 4) ^ (lane & 7)) * 8;
  const int kc1  = (((lane >> 4) + 4) ^ (lane & 7)) * 8;

  f32x4 acc[WRM][WRN] = {};

  auto stage = [&](int buf, int t) {
    #pragma unroll
    for (int i = 0; i < AISS; i++) {
      int row = (wid * AISS + i) * 8 + (lane >> 3);
      __builtin_amdgcn_global_load_lds(
          (const AS1 void*)(A + (size_t)(bm + row) * lda + (size_t)t * 64
                              + (((lane & 7) ^ (row & 7)) * 8)),
          (AS3 void*)(lA + buf * (BM * 64) + (wid * AISS + i) * 512), 16, 0, 0);
    }
    #pragma unroll
    for (int i = 0; i < BISS; i++) {
      int row = (wid * BISS + i) * 8 + (lane >> 3);
      __builtin_amdgcn_global_load_lds(
          (const AS1 void*)(B + (size_t)(bn + row) * ldb + (size_t)t * 64
                              + (((lane & 7) ^ (row & 7)) * 8)),
          (AS3 void*)(lB + buf * (BN * 64) + (wid * BISS + i) * 512), 16, 0, 0);
    }
  };
  auto compute = [&](int buf) {
    const unsigned short* pA = lA + buf * (BM * 64);
    const unsigned short* pB = lB + buf * (BN * 64);
    bf16x8 af[WRM][2], bfv[WRN][2];
    #pragma unroll
    for (int m = 0; m < WRM; m++) {
      int ro = (wr * WM + m * 16 + l15) * 64;
      af[m][0] = *(const bf16x8*)(pA + ro + kc0);
      af[m][1] = *(const bf16x8*)(pA + ro + kc1);
    }
    #pragma unroll
    for (int n = 0; n < WRN; n++) {
      int ro = (wc * WN + n * 16 + l15) * 64;
      bfv[n][0] = *(const bf16x8*)(pB + ro + kc0);
      bfv[n][1] = *(const bf16x8*)(pB + ro + kc1);
    }
    #pragma unroll
    for (int m = 0; m < WRM; m++)
      #pragma unroll
      for (int n = 0; n < WRN; n++) {
        acc[m][n] = __builtin_amdgcn_mfma_f32_16x16x32_bf16(af[m][0], bfv[n][0], acc[m][n], 0, 0, 0);
        acc[m][n] = __builtin_amdgcn_mfma_f32_16x16x32_bf16(af[m][1], bfv[n][1], acc[m][n], 0, 0, 0);
      }
  };

  stage(0, 0); stage(1, 1); stage(2, 2);
  wvm<2 * LOADS>();
  __builtin_amdgcn_s_barrier();

  int bt = 0;
  for (int t = 0; t < NT; ++t) {
    compute(bt);
    __builtin_amdgcn_s_barrier();
    if (t + 1 < NT) {
      if (t + NBUF < NT) stage(bt, t + NBUF);
      int newer = (t + NBUF < NT) ? (NBUF - 1) : (NT - 2 - t);
      if (newer >= 2)      wvm<2 * LOADS>();
      else if (newer == 1) wvm<LOADS>();
      else                 wvm<0>();
      __builtin_amdgcn_s_barrier();
      bt = (bt == NBUF - 1) ? 0 : bt + 1;
    }
  }

  const int r0 = bm + wr * WM;
  const int c0 = bn + wc * WN;
  #pragma unroll
  for (int m = 0; m < WRM; m++)
    #pragma unroll
    for (int n = 0; n < WRN; n++) {
      int col  = c0 + n * 16 + l15;
      int rowb = r0 + m * 16 + ((lane >> 4) << 2);
      #pragma unroll
      for (int r = 0; r < 4; r++) {
        float v = acc[m][n][r] * 2.0f * bw[(rowb + r) * 4 + (col >> 4)];
        outp[(size_t)(rowb + r) * ldo + ocol + col] = f2bf(v);
      }
    }
}

extern "C" void kernel_launch(void* const* d_in, const int* in_sizes, int n_in,
                              void* d_out, int out_size, void* d_ws, size_t ws_size,
                              hipStream_t stream) {
  const float* x  = (const float*)d_in[0];
  const float* bw = (const float*)d_in[1];
  const float* W1 = (const float*)d_in[2];
  const float* b1 = (const float*)d_in[3];
  const float* W2 = (const float*)d_in[4];
  const float* b2 = (const float*)d_in[5];
  const float* A1 = (const float*)d_in[6];
  const float* B1 = (const float*)d_in[7];
  const float* A2 = (const float*)d_in[8];
  const float* B2 = (const float*)d_in[9];
  float* out = (float*)d_out;

  char* w = (char*)d_ws;
  unsigned short* xaug = (unsigned short*)w;  w += (size_t)NR * K1 * 2;       // 18.9 MB
  unsigned short* haug = (unsigned short*)w;  w += (size_t)NR * K2 * 2;       // 69.2 MB
  unsigned short* W1cT = (unsigned short*)w;  w += (size_t)DHID * K1 * 2;     // 2.36 MB
  unsigned short* W2cT = (unsigned short*)w;  w += (size_t)DOUT * K2 * 2;     // 2.16 MB
  unsigned short* A1T  = (unsigned short*)w;  w += (size_t)64 * DIN * 2;
  unsigned short* A2T  = (unsigned short*)w;  w += (size_t)64 * DHID * 2;

  // --- preprocessing ---
  cvt_x_kernel<<<NR * DIN / 4 / 256, 256, 0, stream>>>(x, xaug);
  tconv_kernel<512, 2048, K1, 0><<<dim3(64, 16), 256, 0, stream>>>(W1, W1cT);
  tconv_kernel<64, 2048, K1, 512><<<dim3(64, 2), 256, 0, stream>>>(B1, W1cT);
  tconv_kernel<2048, 512, K2, 0><<<dim3(16, 64), 256, 0, stream>>>(W2, W2cT);
  tconv_kernel<64, 512, K2, 2048><<<dim3(16, 2), 256, 0, stream>>>(B2, W2cT);
  rearrA_kernel<<<128, 256, 0, stream>>>(A1, A1T, 512);
  rearrA_kernel<<<512, 256, 0, stream>>>(A2, A2T, 2048);

  // --- u1 = 2*bw ⊙ (x @ A1cat)  -> xaug[:, 512:576]  (BK=64 ring) ---
  gemmu_kernel<64, 64, 32, 32, 512><<<dim3(NR / 64, 1), 256, 0, stream>>>(
      xaug, K1, A1T, DIN, bw, xaug, K1, 512);
  // --- h = gelu(xaug @ [W1;B1cat] + b1) -> haug[:, 0:2048]
  //     (128x256, 48KB LDS -> 3 blocks/CU, grid 1024) ---
  gemm97_kernel<128, 256, 64, 128, K1, 0><<<dim3(NR / 128, DHID / 256), 256, 0, stream>>>(
      xaug, K1, W1cT, K1, b1, haug, K2, 0);
  // --- u2 = 2*bw ⊙ (h @ A2cat) -> haug[:, 2048:2112]  (BK=64 ring) ---
  gemmu_kernel<64, 64, 32, 32, 2048><<<dim3(NR / 64, 1), 256, 0, stream>>>(
      haug, K2, A2T, DHID, bw, haug, K2, 2048);
  // --- out = haug @ [W2;B2cat] + b2 (fp32)
  //     (64x128, 24KB LDS -> 4 blocks/CU, grid 1024) ---
  gemm97_kernel<64, 128, 32, 64, K2, 1><<<dim3(NR / 64, DOUT / 128), 256, 0, stream>>>(
      haug, K2, W2cT, K2, b2, out, DOUT, 0);
}

// Round 11
// 144.159 us; speedup vs baseline: 1.3036x; 1.3036x over previous
//
#include <hip/hip_runtime.h>
#include <hip/hip_bf16.h>

#define DEV __device__ __forceinline__
#define AS1 __attribute__((address_space(1)))
#define AS3 __attribute__((address_space(3)))

typedef __attribute__((ext_vector_type(8))) short bf16x8;
typedef __attribute__((ext_vector_type(4))) float f32x4;
typedef __attribute__((ext_vector_type(16))) float f32x16;

static constexpr int NR   = 16384;
static constexpr int DIN  = 512;
static constexpr int DHID = 2048;
static constexpr int DOUT = 512;
static constexpr int LR   = 64;          // 4 bands * rank 16
static constexpr int K1   = DIN + LR;    // 576
static constexpr int K2   = DHID + LR;   // 2112

DEV unsigned short f2bf(float f) {
  unsigned u = __float_as_uint(f);
  u += 0x7fffu + ((u >> 16) & 1u);
  return (unsigned short)(u >> 16);
}

// fast GELU: tanh-form, |err vs erf-form| < ~1.5e-3 (well under bf16 quantum of h)
DEV float fast_gelu(float v) {
  float x2 = v * v;
  float a  = -v * __builtin_fmaf(0.10294324f, x2, 2.30220817f);
  float t  = exp2f(a);
  return v * __builtin_amdgcn_rcpf(1.0f + t);
}

template<int N> DEV void wvm() {
  asm volatile("s_waitcnt vmcnt(%0)" :: "i"(N) : "memory");
}

// ==================== fused preprocessing (1 launch) ====================
// block ranges: [0,8192) cvt_x | [8192,9216) W1 tconv | [9216,10240) W2 tconv
// | [10240,10368) B1 | [10368,10400) B2 | [10400,10528) rearrA1 | [10528,11040) rearrA2
DEV void tconv_dev(const float* in, unsigned short* out, int C, int LDO, int CO,
                   int bx, int by, float (*t)[33], int tid) {
  int bc = bx * 32, br = by * 32;
  int tx = tid & 31, ty = tid >> 5;
  #pragma unroll
  for (int i = 0; i < 32; i += 8)
    t[ty + i][tx] = in[(size_t)(br + ty + i) * C + bc + tx];
  __syncthreads();
  #pragma unroll
  for (int i = 0; i < 32; i += 8)
    out[(size_t)(bc + ty + i) * LDO + CO + br + tx] = f2bf(t[tx][ty + i]);
}

__global__ __launch_bounds__(256) void prep_kernel(
    const float* __restrict__ x, unsigned short* __restrict__ xaug,
    const float* __restrict__ W1, const float* __restrict__ B1,
    const float* __restrict__ W2, const float* __restrict__ B2,
    unsigned short* __restrict__ W1cT, unsigned short* __restrict__ W2cT,
    const float* __restrict__ A1, const float* __restrict__ A2,
    unsigned short* __restrict__ A1T, unsigned short* __restrict__ A2T) {
  __shared__ float t[32][33];
  const int b = blockIdx.x, tid = threadIdx.x;
  if (b < 8192) {                      // x fp32 -> bf16 into xaug[:,0:512]
    int i = b * 256 + tid;             // one float4 per thread (exact)
    int e = i * 4;
    int r = e >> 9, c = e & 511;
    float4 v = ((const float4*)x)[i];
    uint2 o;
    o.x = (unsigned)f2bf(v.x) | ((unsigned)f2bf(v.y) << 16);
    o.y = (unsigned)f2bf(v.z) | ((unsigned)f2bf(v.w) << 16);
    *(uint2*)(xaug + (size_t)r * K1 + c) = o;
  } else if (b < 9216) {               // W1 [512][2048] -> W1cT [2048][576] @0
    int bi = b - 8192;
    tconv_dev(W1, W1cT, 2048, K1, 0, bi & 63, bi >> 6, t, tid);
  } else if (b < 10240) {              // W2 [2048][512] -> W2cT [512][2112] @0
    int bi = b - 9216;
    tconv_dev(W2, W2cT, 512, K2, 0, bi & 15, bi >> 4, t, tid);
  } else if (b < 10368) {              // B1cat [64][2048] -> W1cT cols @512
    int bi = b - 10240;
    tconv_dev(B1, W1cT, 2048, K1, 512, bi & 63, bi >> 6, t, tid);
  } else if (b < 10400) {              // B2cat [64][512] -> W2cT cols @2048
    int bi = b - 10368;
    tconv_dev(B2, W2cT, 512, K2, 2048, bi & 15, bi >> 4, t, tid);
  } else if (b < 10528) {              // A1 [4][512][16] -> A1T [64][512]
    int i2 = (b - 10400) * 256 + tid;
    int j = i2 / DIN, i = i2 - j * DIN;
    A1T[i2] = f2bf(A1[((size_t)(j >> 4) * DIN + i) * 16 + (j & 15)]);
  } else {                             // A2 [4][2048][16] -> A2T [64][2048]
    int i2 = (b - 10528) * 256 + tid;
    int j = i2 / DHID, i = i2 - j * DHID;
    A2T[i2] = f2bf(A2[((size_t)(j >> 4) * DHID + i) * 16 + (j & 15)]);
  }
}

// ========== 2-barrier/tile double-buffered GEMM with 32x32x16 MFMA ==========
// R9 skeleton (best measured): per tile t (buf=t&1, nb=buf^1):
//   ldAall+ldB(nh0) | stage A0,A1,B0(t+1) | MFMA nh0 | wvm(6) | BAR
//   stage B1(t+1) | ldB(nh1) | MFMA nh1 | wvm(2) | BAR
// Per-wave FIFO: entry [B1(t):2]; +6 -> wvm6 lands B1(t); +2 -> wvm2 lands
// A0A1B0(t+1), leaves [B1(t+1):2]. Counted waits always followed by barrier.
// 32x32x16 frags: A lane&31=row, lane>>5 = k-half (8 elems); C/D col=lane&31,
// row=(r&3)+8*(r>>2)+4*(lane>>5) (guide m74/m101).
// Geometry: wave grid 2 x WC; wave rows/half = BM/4 (MH = BM/128 m-frags);
// wave cols/half = (BN/2)/WC == 32 (1 n-frag per half).
// EPI: 0 = gelu(acc+bias)->bf16 out ; 1 = acc+bias->fp32 out
template<int BM, int BN, int WAVES, int K, int EPI>
__global__ __launch_bounds__(WAVES * 64, 2) void gemm32_kernel(
    const unsigned short* __restrict__ A, int lda,
    const unsigned short* __restrict__ B, int ldb,
    const float* __restrict__ bias,
    void* __restrict__ outp, int ldo, int ocol) {
  constexpr int THREADS = WAVES * 64;
  constexpr int NT = K / 64;
  constexpr int AL = BM * 4 / THREADS;   // gload_lds/thread per A half (=2)
  constexpr int BL = BN * 4 / THREADS;   // per B half (=2)
  constexpr int HA = (BM / 2) * 64;      // elems per half-slot
  constexpr int HB = (BN / 2) * 64;
  constexpr int MH = BM / 128;           // 32-row m-frags per half per wave
  constexpr int WC = WAVES / 2;
  static_assert(NT >= 2 && AL == 2 && BL == 2 && (BN / 2) / WC == 32, "geometry");
  __shared__ __align__(16) unsigned short lA[4 * HA];   // [buf][half]
  __shared__ __align__(16) unsigned short lB[4 * HB];

  const int tid  = threadIdx.x;
  const int w    = tid >> 6, lane = tid & 63;
  const int wr   = w / WC, wc = w % WC;
  const int bm   = blockIdx.x * BM, bn = blockIdx.y * BN;
  const int l31  = lane & 31;
  const int kh   = lane >> 5;            // k-half within K=16 step
  const int swz  = lane & 7;             // == row&7 for all frag rows (base %32==0)

  f32x16 acc[2][2][MH] = {};             // [mh][nh][m]
  bf16x8 af[2][MH][4];                   // [mh][m][ks] -- all A resident
  bf16x8 bfv[4];                         // [ks] -- current nh only

  auto stageA = [&](int buf, int half, int t) {
    #pragma unroll
    for (int i = 0; i < AL; ++i) {
      int row = w * (AL * 8) + i * 8 + (lane >> 3);
      __builtin_amdgcn_global_load_lds(
          (const AS1 void*)(A + (size_t)(bm + half * (BM / 2) + row) * lda
                              + (size_t)t * 64 + (((lane & 7) ^ (row & 7)) * 8)),
          (AS3 void*)(lA + (buf * 2 + half) * HA + (w * AL + i) * 512),
          16, 0, 0);
    }
  };
  auto stageB = [&](int buf, int half, int t) {
    #pragma unroll
    for (int i = 0; i < BL; ++i) {
      int row = w * (BL * 8) + i * 8 + (lane >> 3);
      __builtin_amdgcn_global_load_lds(
          (const AS1 void*)(B + (size_t)(bn + half * (BN / 2) + row) * ldb
                              + (size_t)t * 64 + (((lane & 7) ^ (row & 7)) * 8)),
          (AS3 void*)(lB + (buf * 2 + half) * HB + (w * BL + i) * 512),
          16, 0, 0);
    }
  };
  auto ldAall = [&](int buf) {
    #pragma unroll
    for (int mh = 0; mh < 2; ++mh) {
      const unsigned short* sA = lA + (buf * 2 + mh) * HA;
      #pragma unroll
      for (int m = 0; m < MH; ++m) {
        int ro = (wr * (BM / 4) + m * 32 + l31) * 64;
        #pragma unroll
        for (int ks = 0; ks < 4; ++ks)
          af[mh][m][ks] = *(const bf16x8*)(sA + ro + (((2 * ks + kh) ^ swz) * 8));
      }
    }
  };
  auto ldB = [&](int buf, int nh) {
    const unsigned short* sB = lB + (buf * 2 + nh) * HB;
    int ro = (wc * 32 + l31) * 64;
    #pragma unroll
    for (int ks = 0; ks < 4; ++ks)
      bfv[ks] = *(const bf16x8*)(sB + ro + (((2 * ks + kh) ^ swz) * 8));
  };

#define MFMA_C(nh)                                                               \
  __builtin_amdgcn_s_setprio(1);                                                 \
  _Pragma("unroll")                                                              \
  for (int mh = 0; mh < 2; ++mh)                                                 \
    _Pragma("unroll")                                                            \
    for (int m = 0; m < MH; ++m)                                                 \
      _Pragma("unroll")                                                          \
      for (int ks = 0; ks < 4; ++ks)                                             \
        acc[mh][nh][m] = __builtin_amdgcn_mfma_f32_32x32x16_bf16(                \
            af[mh][m][ks], bfv[ks], acc[mh][nh][m], 0, 0, 0);                    \
  __builtin_amdgcn_s_setprio(0);

#define BAR() __builtin_amdgcn_s_barrier()

  // prologue: stage tile0 (A0,A1,B0,B1); land A0,A1,B0; keep B1 in flight
  stageA(0, 0, 0); stageA(0, 1, 0); stageB(0, 0, 0); stageB(0, 1, 0);
  wvm<2>();
  BAR();

  for (int t = 0; t < NT; ++t) {
    const int buf = t & 1, nb = buf ^ 1;
    const bool more = (t + 1 < NT);
    ldAall(buf);
    ldB(buf, 0);
    if (more) { stageA(nb, 0, t + 1); stageA(nb, 1, t + 1); stageB(nb, 0, t + 1); }
    MFMA_C(0);
    if (more) wvm<6>(); else wvm<0>();   // B1(t) landed (issued mid-tile t-1)
    BAR();                               // B1(t) visible to all waves
    if (more) stageB(nb, 1, t + 1);
    ldB(buf, 1);
    MFMA_C(1);
    if (more) {
      wvm<2>();                          // A0,A1,B0(t+1) landed
      BAR();
    }
  }
#undef MFMA_C
#undef BAR

  // epilogue: 32x32 C/D layout col=lane&31, row=(r&3)+8*(r>>2)+4*(lane>>5)
  float biasv[2];
  #pragma unroll
  for (int nh = 0; nh < 2; ++nh)
    biasv[nh] = bias[bn + nh * (BN / 2) + wc * 32 + l31];

  #pragma unroll
  for (int mh = 0; mh < 2; ++mh)
    #pragma unroll
    for (int nh = 0; nh < 2; ++nh)
      #pragma unroll
      for (int m = 0; m < MH; ++m) {
        int col  = bn + nh * (BN / 2) + wc * 32 + l31;
        int rowb = bm + mh * (BM / 2) + wr * (BM / 4) + m * 32 + 4 * (lane >> 5);
        #pragma unroll
        for (int r = 0; r < 16; ++r) {
          float v = acc[mh][nh][m][r];
          int row = rowb + (r & 3) + 8 * (r >> 2);
          if (EPI == 0) {
            v = fast_gelu(v + biasv[nh]);
            ((unsigned short*)outp)[(size_t)row * ldo + ocol + col] = f2bf(v);
          } else {
            v += biasv[nh];
            ((float*)outp)[(size_t)row * ldo + col] = v;
          }
        }
      }
}

// ============ small GEMM for LoRA u-projections: BK=64, 3-buffer counted ring ============
// (validated R9 structure, 16x16x32) EPI2: acc*2*bw[row][col>>4] -> bf16 out
template<int BM, int BN, int WM, int WN, int K>
__global__ __launch_bounds__(256) void gemmu_kernel(
    const unsigned short* __restrict__ A, int lda,
    const unsigned short* __restrict__ B, int ldb,
    const float* __restrict__ bw,
    unsigned short* __restrict__ outp, int ldo, int ocol) {
  constexpr int WRM = WM / 16, WRN = WN / 16;
  constexpr int NWN = BN / WN;
  constexpr int NT  = K / 64;
  constexpr int NBUF = 3;
  constexpr int AISS = BM * 64 * 2 / 4096;
  constexpr int BISS = BN * 64 * 2 / 4096;
  constexpr int LOADS = AISS + BISS;
  static_assert((BM / WM) * (BN / WN) == 4 && NT >= NBUF, "geometry");
  __shared__ __align__(16) unsigned short lA[NBUF * BM * 64];
  __shared__ __align__(16) unsigned short lB[NBUF * BN * 64];

  const int tid  = threadIdx.x;
  const int wid  = tid >> 6, lane = tid & 63;
  const int wr   = wid / NWN, wc = wid % NWN;
  const int bm   = blockIdx.x * BM, bn = blockIdx.y * BN;
  const int l15  = lane & 15;
  const int kc0  = ((lane >> 4) ^ (lane & 7)) * 8;
  const int kc1  = (((lane >> 4) + 4) ^ (lane & 7)) * 8;

  f32x4 acc[WRM][WRN] = {};

  auto stage = [&](int buf, int t) {
    #pragma unroll
    for (int i = 0; i < AISS; i++) {
      int row = (wid * AISS + i) * 8 + (lane >> 3);
      __builtin_amdgcn_global_load_lds(
          (const AS1 void*)(A + (size_t)(bm + row) * lda + (size_t)t * 64
                              + (((lane & 7) ^ (row & 7)) * 8)),
          (AS3 void*)(lA + buf * (BM * 64) + (wid * AISS + i) * 512), 16, 0, 0);
    }
    #pragma unroll
    for (int i = 0; i < BISS; i++) {
      int row = (wid * BISS + i) * 8 + (lane >> 3);
      __builtin_amdgcn_global_load_lds(
          (const AS1 void*)(B + (size_t)(bn + row) * ldb + (size_t)t * 64
                              + (((lane & 7) ^ (row & 7)) * 8)),
          (AS3 void*)(lB + buf * (BN * 64) + (wid * BISS + i) * 512), 16, 0, 0);
    }
  };
  auto compute = [&](int buf) {
    const unsigned short* pA = lA + buf * (BM * 64);
    const unsigned short* pB = lB + buf * (BN * 64);
    bf16x8 af[WRM][2], bfv[WRN][2];
    #pragma unroll
    for (int m = 0; m < WRM; m++) {
      int ro = (wr * WM + m * 16 + l15) * 64;
      af[m][0] = *(const bf16x8*)(pA + ro + kc0);
      af[m][1] = *(const bf16x8*)(pA + ro + kc1);
    }
    #pragma unroll
    for (int n = 0; n < WRN; n++) {
      int ro = (wc * WN + n * 16 + l15) * 64;
      bfv[n][0] = *(const bf16x8*)(pB + ro + kc0);
      bfv[n][1] = *(const bf16x8*)(pB + ro + kc1);
    }
    #pragma unroll
    for (int m = 0; m < WRM; m++)
      #pragma unroll
      for (int n = 0; n < WRN; n++) {
        acc[m][n] = __builtin_amdgcn_mfma_f32_16x16x32_bf16(af[m][0], bfv[n][0], acc[m][n], 0, 0, 0);
        acc[m][n] = __builtin_amdgcn_mfma_f32_16x16x32_bf16(af[m][1], bfv[n][1], acc[m][n], 0, 0, 0);
      }
  };

  stage(0, 0); stage(1, 1); stage(2, 2);
  wvm<2 * LOADS>();
  __builtin_amdgcn_s_barrier();

  int bt = 0;
  for (int t = 0; t < NT; ++t) {
    compute(bt);
    __builtin_amdgcn_s_barrier();
    if (t + 1 < NT) {
      if (t + NBUF < NT) stage(bt, t + NBUF);
      int newer = (t + NBUF < NT) ? (NBUF - 1) : (NT - 2 - t);
      if (newer >= 2)      wvm<2 * LOADS>();
      else if (newer == 1) wvm<LOADS>();
      else                 wvm<0>();
      __builtin_amdgcn_s_barrier();
      bt = (bt == NBUF - 1) ? 0 : bt + 1;
    }
  }

  const int r0 = bm + wr * WM;
  const int c0 = bn + wc * WN;
  #pragma unroll
  for (int m = 0; m < WRM; m++)
    #pragma unroll
    for (int n = 0; n < WRN; n++) {
      int col  = c0 + n * 16 + l15;
      int rowb = r0 + m * 16 + ((lane >> 4) << 2);
      #pragma unroll
      for (int r = 0; r < 4; r++) {
        float v = acc[m][n][r] * 2.0f * bw[(rowb + r) * 4 + (col >> 4)];
        outp[(size_t)(rowb + r) * ldo + ocol + col] = f2bf(v);
      }
    }
}

extern "C" void kernel_launch(void* const* d_in, const int* in_sizes, int n_in,
                              void* d_out, int out_size, void* d_ws, size_t ws_size,
                              hipStream_t stream) {
  const float* x  = (const float*)d_in[0];
  const float* bw = (const float*)d_in[1];
  const float* W1 = (const float*)d_in[2];
  const float* b1 = (const float*)d_in[3];
  const float* W2 = (const float*)d_in[4];
  const float* b2 = (const float*)d_in[5];
  const float* A1 = (const float*)d_in[6];
  const float* B1 = (const float*)d_in[7];
  const float* A2 = (const float*)d_in[8];
  const float* B2 = (const float*)d_in[9];
  float* out = (float*)d_out;

  char* w = (char*)d_ws;
  unsigned short* xaug = (unsigned short*)w;  w += (size_t)NR * K1 * 2;       // 18.9 MB
  unsigned short* haug = (unsigned short*)w;  w += (size_t)NR * K2 * 2;       // 69.2 MB
  unsigned short* W1cT = (unsigned short*)w;  w += (size_t)DHID * K1 * 2;     // 2.36 MB
  unsigned short* W2cT = (unsigned short*)w;  w += (size_t)DOUT * K2 * 2;     // 2.16 MB
  unsigned short* A1T  = (unsigned short*)w;  w += (size_t)64 * DIN * 2;
  unsigned short* A2T  = (unsigned short*)w;  w += (size_t)64 * DHID * 2;

  // --- fused preprocessing: 1 launch ---
  prep_kernel<<<11040, 256, 0, stream>>>(x, xaug, W1, B1, W2, B2,
                                         W1cT, W2cT, A1, A2, A1T, A2T);

  // --- u1 = 2*bw ⊙ (x @ A1cat)  -> xaug[:, 512:576] ---
  gemmu_kernel<64, 64, 32, 32, 512><<<dim3(NR / 64, 1), 256, 0, stream>>>(
      xaug, K1, A1T, DIN, bw, xaug, K1, 512);
  // --- h = gelu(xaug @ [W1;B1cat] + b1) -> haug[:, 0:2048]  (256x256, 8 waves, 32x32 MFMA) ---
  gemm32_kernel<256, 256, 8, K1, 0><<<dim3(NR / 256, DHID / 256), 512, 0, stream>>>(
      xaug, K1, W1cT, K1, b1, haug, K2, 0);
  // --- u2 = 2*bw ⊙ (h @ A2cat) -> haug[:, 2048:2112] ---
  gemmu_kernel<64, 64, 32, 32, 2048><<<dim3(NR / 64, 1), 256, 0, stream>>>(
      haug, K2, A2T, DHID, bw, haug, K2, 2048);
  // --- out = haug @ [W2;B2cat] + b2 (fp32)  (128x128, 4 waves, 32x32 MFMA, 2 blocks/CU) ---
  gemm32_kernel<128, 128, 4, K2, 1><<<dim3(NR / 128, DOUT / 128), 256, 0, stream>>>(
      haug, K2, W2cT, K2, b2, out, DOUT, 0);
}

// Round 12
// 139.465 us; speedup vs baseline: 1.3475x; 1.0337x over previous
//
#include <hip/hip_runtime.h>
#include <hip/hip_bf16.h>

#define DEV __device__ __forceinline__
#define AS1 __attribute__((address_space(1)))
#define AS3 __attribute__((address_space(3)))

typedef __attribute__((ext_vector_type(8))) short bf16x8;
typedef __attribute__((ext_vector_type(4))) float f32x4;

static constexpr int NR   = 16384;
static constexpr int DIN  = 512;
static constexpr int DHID = 2048;
static constexpr int DOUT = 512;
static constexpr int LR   = 64;          // 4 bands * rank 16
static constexpr int K1   = DIN + LR;    // 576
static constexpr int K2   = DHID + LR;   // 2112

DEV unsigned short f2bf(float f) {
  unsigned u = __float_as_uint(f);
  u += 0x7fffu + ((u >> 16) & 1u);
  return (unsigned short)(u >> 16);
}

// fast GELU: tanh-form, |err vs erf-form| < ~1.5e-3 (well under bf16 quantum of h)
DEV float fast_gelu(float v) {
  float x2 = v * v;
  float a  = -v * __builtin_fmaf(0.10294324f, x2, 2.30220817f);
  float t  = exp2f(a);
  return v * __builtin_amdgcn_rcpf(1.0f + t);
}

template<int N> DEV void wvm() {
  asm volatile("s_waitcnt vmcnt(%0)" :: "i"(N) : "memory");
}

// ==================== fused weight preprocessing (1 launch) ====================
// [0,1024) W1 tconv | [1024,2048) W2 tconv | [2048,2176) B1 | [2176,2208) B2
// | [2208,2336) rearrA1 | [2336,2848) rearrA2
DEV void tconv_dev(const float* in, unsigned short* out, int C, int LDO, int CO,
                   int bx, int by, float (*t)[33], int tid) {
  int bc = bx * 32, br = by * 32;
  int tx = tid & 31, ty = tid >> 5;
  #pragma unroll
  for (int i = 0; i < 32; i += 8)
    t[ty + i][tx] = in[(size_t)(br + ty + i) * C + bc + tx];
  __syncthreads();
  #pragma unroll
  for (int i = 0; i < 32; i += 8)
    out[(size_t)(bc + ty + i) * LDO + CO + br + tx] = f2bf(t[tx][ty + i]);
}

__global__ __launch_bounds__(256) void prep_kernel(
    const float* __restrict__ W1, const float* __restrict__ B1,
    const float* __restrict__ W2, const float* __restrict__ B2,
    unsigned short* __restrict__ W1cT, unsigned short* __restrict__ W2cT,
    const float* __restrict__ A1, const float* __restrict__ A2,
    unsigned short* __restrict__ A1T, unsigned short* __restrict__ A2T) {
  __shared__ float t[32][33];
  const int b = blockIdx.x, tid = threadIdx.x;
  if (b < 1024) {                      // W1 [512][2048] -> W1cT [2048][576] @0
    tconv_dev(W1, W1cT, 2048, K1, 0, b & 63, b >> 6, t, tid);
  } else if (b < 2048) {               // W2 [2048][512] -> W2cT [512][2112] @0
    int bi = b - 1024;
    tconv_dev(W2, W2cT, 512, K2, 0, bi & 15, bi >> 4, t, tid);
  } else if (b < 2176) {               // B1cat [64][2048] -> W1cT cols @512
    int bi = b - 2048;
    tconv_dev(B1, W1cT, 2048, K1, 512, bi & 63, bi >> 6, t, tid);
  } else if (b < 2208) {               // B2cat [64][512] -> W2cT cols @2048
    int bi = b - 2176;
    tconv_dev(B2, W2cT, 512, K2, 2048, bi & 15, bi >> 4, t, tid);
  } else if (b < 2336) {               // A1 [4][512][16] -> A1T [64][512]
    int i2 = (b - 2208) * 256 + tid;
    int j = i2 / DIN, i = i2 - j * DIN;
    A1T[i2] = f2bf(A1[((size_t)(j >> 4) * DIN + i) * 16 + (j & 15)]);
  } else {                             // A2 [4][2048][16] -> A2T [64][2048]
    int i2 = (b - 2336) * 256 + tid;
    int j = i2 / DHID, i = i2 - j * DHID;
    A2T[i2] = f2bf(A2[((size_t)(j >> 4) * DHID + i) * 16 + (j & 15)]);
  }
}

// ========== fused cvt_x + u1: block = 64 rows, loops K=512 in 8 tiles ==========
// Per tile: read x fp32 (coalesced float4), convert, write bf16 to xaug AND to
// swizzled LDS; stage A1T tile via gload_lds; MFMA u1-partial. After loop:
// u1 *= 2*bw, write to xaug[:,512:576].
__global__ __launch_bounds__(256) void u1cvt_kernel(
    const float* __restrict__ x, const float* __restrict__ bw,
    const unsigned short* __restrict__ A1T, unsigned short* __restrict__ xaug) {
  __shared__ __align__(16) unsigned short lX[64 * 64];
  __shared__ __align__(16) unsigned short lW[64 * 64];
  const int tid = threadIdx.x;
  const int w = tid >> 6, lane = tid & 63;
  const int bm = blockIdx.x * 64;
  const int l15 = lane & 15;
  const int kc0 = ((lane >> 4) ^ (lane & 7)) * 8;
  const int kc1 = (((lane >> 4) + 4) ^ (lane & 7)) * 8;

  f32x4 acc[4] = {};   // u1: 16 rows (this wave) x 4 n-frags of 16 cols

  for (int kt = 0; kt < 8; ++kt) {
    // stage A1T tile [64 j][64 k] (swizzled source, linear LDS)
    #pragma unroll
    for (int i = 0; i < 2; ++i) {
      int row = i * 32 + w * 8 + (lane >> 3);
      __builtin_amdgcn_global_load_lds(
          (const AS1 void*)(A1T + (size_t)row * DIN + kt * 64
                              + (((lane & 7) ^ (row & 7)) * 8)),
          (AS3 void*)(lW + (i * 32 + w * 8) * 64 + lane * 8), 16, 0, 0);
    }
    // read x fp32, convert, write xaug + LDS (swizzled)
    #pragma unroll
    for (int p = 0; p < 4; ++p) {
      int row = p * 16 + (tid >> 4);
      int col = (tid & 15) * 4;
      float4 v = *(const float4*)(x + (size_t)(bm + row) * DIN + kt * 64 + col);
      uint2 o;
      o.x = (unsigned)f2bf(v.x) | ((unsigned)f2bf(v.y) << 16);
      o.y = (unsigned)f2bf(v.z) | ((unsigned)f2bf(v.w) << 16);
      *(uint2*)(xaug + (size_t)(bm + row) * K1 + kt * 64 + col) = o;
      // LDS: byte = row*128 + ((col>>3)^(row&7))*16 + (col&7)*2
      char* p3 = (char*)lX + row * 128 + (((col >> 3) ^ (row & 7)) << 4) + ((col & 7) << 1);
      *(uint2*)p3 = o;
    }
    __syncthreads();   // ds_writes + gload_lds visible
    bf16x8 af0 = *(const bf16x8*)(lX + (w * 16 + l15) * 64 + kc0);
    bf16x8 af1 = *(const bf16x8*)(lX + (w * 16 + l15) * 64 + kc1);
    #pragma unroll
    for (int n = 0; n < 4; ++n) {
      bf16x8 b0 = *(const bf16x8*)(lW + (n * 16 + l15) * 64 + kc0);
      bf16x8 b1 = *(const bf16x8*)(lW + (n * 16 + l15) * 64 + kc1);
      acc[n] = __builtin_amdgcn_mfma_f32_16x16x32_bf16(af0, b0, acc[n], 0, 0, 0);
      acc[n] = __builtin_amdgcn_mfma_f32_16x16x32_bf16(af1, b1, acc[n], 0, 0, 0);
    }
    __syncthreads();   // reads done before next tile overwrites
  }

  // scale + store u1 -> xaug[:, 512:576]; band = n (cols n*16..)
  #pragma unroll
  for (int n = 0; n < 4; ++n) {
    int col = n * 16 + l15;
    #pragma unroll
    for (int r = 0; r < 4; ++r) {
      int row = bm + w * 16 + ((lane >> 4) << 2) + r;
      float v = acc[n][r] * 2.0f * bw[row * 4 + n];
      xaug[(size_t)row * K1 + 512 + col] = f2bf(v);
    }
  }
}

// ========== 2-barrier/tile double-buffered MFMA GEMM (R9 skeleton, generalized) ==========
// Per tile t (buf=t&1, nb=buf^1):
//   ldAall+ldB(nh0) | stage A0,A1,B0(t+1) [2AL+BL loads] | MFMA nh0
//   wvm(2AL+BL) [lands B1(t)] | BAR | stage B1(t+1) | ldB(nh1) | MFMA nh1
//   wvm(BL) [lands A0,A1,B0(t+1)] | BAR
// Per-wave FIFO: entry [B1(t):BL]; +(2AL+BL) -> wvm(2AL+BL); +BL -> wvm(BL).
// EPI: 0 = gelu(acc+bias)->bf16 out ; 1 = acc+bias->fp32 out
template<int BM, int BN, int WAVES, int K, int EPI>
__global__ __launch_bounds__(WAVES * 64, 2) void gemmx_kernel(
    const unsigned short* __restrict__ A, int lda,
    const unsigned short* __restrict__ B, int ldb,
    const float* __restrict__ bias,
    void* __restrict__ outp, int ldo, int ocol) {
  constexpr int THREADS = WAVES * 64;
  constexpr int NT = K / 64;
  constexpr int AL = BM * 4 / THREADS;   // gload_lds/thread per A half (1|2)
  constexpr int BL = BN * 4 / THREADS;   // per B half
  constexpr int HA = (BM / 2) * 64;      // elems per half-slot
  constexpr int HB = (BN / 2) * 64;
  constexpr int MQ = BM / 64;            // m-frags per quadrant per wave
  constexpr int WC = WAVES / 2;
  static_assert(NT >= 2 && AL >= 1 && BL >= 1 && (BN / 2) / WC == 32, "geometry");
  __shared__ __align__(16) unsigned short lA[4 * HA];   // [buf][half]
  __shared__ __align__(16) unsigned short lB[4 * HB];

  const int tid  = threadIdx.x;
  const int w    = tid >> 6, lane = tid & 63;
  const int wr   = w / WC, wc = w % WC;
  const int bm   = blockIdx.x * BM, bn = blockIdx.y * BN;
  const int l15  = lane & 15;
  const int kc0  = ((lane >> 4) ^ (lane & 7)) * 8;        // kk=0 chunk (swizzled)
  const int kc1  = (((lane >> 4) + 4) ^ (lane & 7)) * 8;  // kk=1 chunk

  f32x4 acc[2][2][MQ][2] = {};   // [mh][nh][m][n]
  bf16x8 af[2][MQ][2];           // [mh][m][kk] -- BOTH A halves resident
  bf16x8 bfv[2][2];              // [n][kk] -- current nh only

  auto stageA = [&](int buf, int half, int t) {
    #pragma unroll
    for (int i = 0; i < AL; ++i) {
      int row = w * (AL * 8) + i * 8 + (lane >> 3);
      __builtin_amdgcn_global_load_lds(
          (const AS1 void*)(A + (size_t)(bm + half * (BM / 2) + row) * lda
                              + (size_t)t * 64 + (((lane & 7) ^ (row & 7)) * 8)),
          (AS3 void*)(lA + (buf * 2 + half) * HA + (w * AL + i) * 512),
          16, 0, 0);
    }
  };
  auto stageB = [&](int buf, int half, int t) {
    #pragma unroll
    for (int i = 0; i < BL; ++i) {
      int row = w * (BL * 8) + i * 8 + (lane >> 3);
      __builtin_amdgcn_global_load_lds(
          (const AS1 void*)(B + (size_t)(bn + half * (BN / 2) + row) * ldb
                              + (size_t)t * 64 + (((lane & 7) ^ (row & 7)) * 8)),
          (AS3 void*)(lB + (buf * 2 + half) * HB + (w * BL + i) * 512),
          16, 0, 0);
    }
  };
  auto ldAall = [&](int buf) {
    #pragma unroll
    for (int mh = 0; mh < 2; ++mh) {
      const unsigned short* sA = lA + (buf * 2 + mh) * HA;
      #pragma unroll
      for (int m = 0; m < MQ; ++m) {
        int ro = (wr * (BM / 4) + m * 16 + l15) * 64;
        af[mh][m][0] = *(const bf16x8*)(sA + ro + kc0);
        af[mh][m][1] = *(const bf16x8*)(sA + ro + kc1);
      }
    }
  };
  auto ldB = [&](int buf, int nh) {
    const unsigned short* sB = lB + (buf * 2 + nh) * HB;
    #pragma unroll
    for (int n = 0; n < 2; ++n) {
      int ro = (wc * 32 + n * 16 + l15) * 64;
      bfv[n][0] = *(const bf16x8*)(sB + ro + kc0);
      bfv[n][1] = *(const bf16x8*)(sB + ro + kc1);
    }
  };

#define MFMA_Q(mh, nh)                                                           \
  __builtin_amdgcn_s_setprio(1);                                                 \
  _Pragma("unroll")                                                              \
  for (int m = 0; m < MQ; ++m)                                                   \
    _Pragma("unroll")                                                            \
    for (int n = 0; n < 2; ++n) {                                                \
      acc[mh][nh][m][n] = __builtin_amdgcn_mfma_f32_16x16x32_bf16(               \
          af[mh][m][0], bfv[n][0], acc[mh][nh][m][n], 0, 0, 0);                  \
      acc[mh][nh][m][n] = __builtin_amdgcn_mfma_f32_16x16x32_bf16(               \
          af[mh][m][1], bfv[n][1], acc[mh][nh][m][n], 0, 0, 0);                  \
    }                                                                            \
  __builtin_amdgcn_s_setprio(0);

#define BAR() __builtin_amdgcn_s_barrier()

  // prologue: stage tile0 (A0,A1,B0,B1); land A0,A1,B0; keep B1 in flight
  stageA(0, 0, 0); stageA(0, 1, 0); stageB(0, 0, 0); stageB(0, 1, 0);
  wvm<BL>();
  BAR();

  for (int t = 0; t < NT; ++t) {
    const int buf = t & 1, nb = buf ^ 1;
    const bool more = (t + 1 < NT);
    ldAall(buf);
    ldB(buf, 0);
    if (more) { stageA(nb, 0, t + 1); stageA(nb, 1, t + 1); stageB(nb, 0, t + 1); }
    MFMA_Q(0, 0);
    MFMA_Q(1, 0);
    if (more) wvm<2 * AL + BL>(); else wvm<0>();   // B1(t) landed
    BAR();                                          // B1(t) visible to all waves
    if (more) stageB(nb, 1, t + 1);
    ldB(buf, 1);
    MFMA_Q(0, 1);
    MFMA_Q(1, 1);
    if (more) {
      wvm<BL>();                                    // A0,A1,B0(t+1) landed
      BAR();
    }
  }
#undef MFMA_Q
#undef BAR

  // epilogue: C/D layout col=lane&15, row=(lane>>4)*4+reg
  float biasv[2][2];
  #pragma unroll
  for (int nh = 0; nh < 2; ++nh)
    #pragma unroll
    for (int n = 0; n < 2; ++n)
      biasv[nh][n] = bias[bn + nh * (BN / 2) + wc * 32 + n * 16 + l15];

  #pragma unroll
  for (int mh = 0; mh < 2; ++mh)
    #pragma unroll
    for (int nh = 0; nh < 2; ++nh)
      #pragma unroll
      for (int m = 0; m < MQ; ++m)
        #pragma unroll
        for (int n = 0; n < 2; ++n) {
          int col  = bn + nh * (BN / 2) + wc * 32 + n * 16 + l15;
          int rowb = bm + mh * (BM / 2) + wr * (BM / 4) + m * 16 + ((lane >> 4) << 2);
          #pragma unroll
          for (int r = 0; r < 4; ++r) {
            float v = acc[mh][nh][m][n][r];
            int row = rowb + r;
            if (EPI == 0) {
              v = fast_gelu(v + biasv[nh][n]);
              ((unsigned short*)outp)[(size_t)row * ldo + ocol + col] = f2bf(v);
            } else {
              v += biasv[nh][n];
              ((float*)outp)[(size_t)row * ldo + col] = v;
            }
          }
        }
}

// ============ small GEMM for LoRA u2 projection: BK=64, 3-buffer counted ring ============
// EPI2: acc*2*bw[row][col>>4] -> bf16 out at col offset
template<int BM, int BN, int WM, int WN, int K>
__global__ __launch_bounds__(256) void gemmu_kernel(
    const unsigned short* __restrict__ A, int lda,
    const unsigned short* __restrict__ B, int ldb,
    const float* __restrict__ bw,
    unsigned short* __restrict__ outp, int ldo, int ocol) {
  constexpr int WRM = WM / 16, WRN = WN / 16;
  constexpr int NWN = BN / WN;
  constexpr int NT  = K / 64;
  constexpr int NBUF = 3;
  constexpr int AISS = BM * 64 * 2 / 4096;
  constexpr int BISS = BN * 64 * 2 / 4096;
  constexpr int LOADS = AISS + BISS;
  static_assert((BM / WM) * (BN / WN) == 4 && NT >= NBUF, "geometry");
  __shared__ __align__(16) unsigned short lA[NBUF * BM * 64];
  __shared__ __align__(16) unsigned short lB[NBUF * BN * 64];

  const int tid  = threadIdx.x;
  const int wid  = tid >> 6, lane = tid & 63;
  const int wr   = wid / NWN, wc = wid % NWN;
  const int bm   = blockIdx.x * BM, bn = blockIdx.y * BN;
  const int l15  = lane & 15;
  const int kc0  = ((lane >> 4) ^ (lane & 7)) * 8;
  const int kc1  = (((lane >> 4) + 4) ^ (lane & 7)) * 8;

  f32x4 acc[WRM][WRN] = {};

  auto stage = [&](int buf, int t) {
    #pragma unroll
    for (int i = 0; i < AISS; i++) {
      int row = (wid * AISS + i) * 8 + (lane >> 3);
      __builtin_amdgcn_global_load_lds(
          (const AS1 void*)(A + (size_t)(bm + row) * lda + (size_t)t * 64
                              + (((lane & 7) ^ (row & 7)) * 8)),
          (AS3 void*)(lA + buf * (BM * 64) + (wid * AISS + i) * 512), 16, 0, 0);
    }
    #pragma unroll
    for (int i = 0; i < BISS; i++) {
      int row = (wid * BISS + i) * 8 + (lane >> 3);
      __builtin_amdgcn_global_load_lds(
          (const AS1 void*)(B + (size_t)(bn + row) * ldb + (size_t)t * 64
                              + (((lane & 7) ^ (row & 7)) * 8)),
          (AS3 void*)(lB + buf * (BN * 64) + (wid * BISS + i) * 512), 16, 0, 0);
    }
  };
  auto compute = [&](int buf) {
    const unsigned short* pA = lA + buf * (BM * 64);
    const unsigned short* pB = lB + buf * (BN * 64);
    bf16x8 af[WRM][2], bfv[WRN][2];
    #pragma unroll
    for (int m = 0; m < WRM; m++) {
      int ro = (wr * WM + m * 16 + l15) * 64;
      af[m][0] = *(const bf16x8*)(pA + ro + kc0);
      af[m][1] = *(const bf16x8*)(pA + ro + kc1);
    }
    #pragma unroll
    for (int n = 0; n < WRN; n++) {
      int ro = (wc * WN + n * 16 + l15) * 64;
      bfv[n][0] = *(const bf16x8*)(pB + ro + kc0);
      bfv[n][1] = *(const bf16x8*)(pB + ro + kc1);
    }
    #pragma unroll
    for (int m = 0; m < WRM; m++)
      #pragma unroll
      for (int n = 0; n < WRN; n++) {
        acc[m][n] = __builtin_amdgcn_mfma_f32_16x16x32_bf16(af[m][0], bfv[n][0], acc[m][n], 0, 0, 0);
        acc[m][n] = __builtin_amdgcn_mfma_f32_16x16x32_bf16(af[m][1], bfv[n][1], acc[m][n], 0, 0, 0);
      }
  };

  stage(0, 0); stage(1, 1); stage(2, 2);
  wvm<2 * LOADS>();
  __builtin_amdgcn_s_barrier();

  int bt = 0;
  for (int t = 0; t < NT; ++t) {
    compute(bt);
    __builtin_amdgcn_s_barrier();
    if (t + 1 < NT) {
      if (t + NBUF < NT) stage(bt, t + NBUF);
      int newer = (t + NBUF < NT) ? (NBUF - 1) : (NT - 2 - t);
      if (newer >= 2)      wvm<2 * LOADS>();
      else if (newer == 1) wvm<LOADS>();
      else                 wvm<0>();
      __builtin_amdgcn_s_barrier();
      bt = (bt == NBUF - 1) ? 0 : bt + 1;
    }
  }

  const int r0 = bm + wr * WM;
  const int c0 = bn + wc * WN;
  #pragma unroll
  for (int m = 0; m < WRM; m++)
    #pragma unroll
    for (int n = 0; n < WRN; n++) {
      int col  = c0 + n * 16 + l15;
      int rowb = r0 + m * 16 + ((lane >> 4) << 2);
      #pragma unroll
      for (int r = 0; r < 4; r++) {
        float v = acc[m][n][r] * 2.0f * bw[(rowb + r) * 4 + (col >> 4)];
        outp[(size_t)(rowb + r) * ldo + ocol + col] = f2bf(v);
      }
    }
}

extern "C" void kernel_launch(void* const* d_in, const int* in_sizes, int n_in,
                              void* d_out, int out_size, void* d_ws, size_t ws_size,
                              hipStream_t stream) {
  const float* x  = (const float*)d_in[0];
  const float* bw = (const float*)d_in[1];
  const float* W1 = (const float*)d_in[2];
  const float* b1 = (const float*)d_in[3];
  const float* W2 = (const float*)d_in[4];
  const float* b2 = (const float*)d_in[5];
  const float* A1 = (const float*)d_in[6];
  const float* B1 = (const float*)d_in[7];
  const float* A2 = (const float*)d_in[8];
  const float* B2 = (const float*)d_in[9];
  float* out = (float*)d_out;

  char* w = (char*)d_ws;
  unsigned short* xaug = (unsigned short*)w;  w += (size_t)NR * K1 * 2;       // 18.9 MB
  unsigned short* haug = (unsigned short*)w;  w += (size_t)NR * K2 * 2;       // 69.2 MB
  unsigned short* W1cT = (unsigned short*)w;  w += (size_t)DHID * K1 * 2;     // 2.36 MB
  unsigned short* W2cT = (unsigned short*)w;  w += (size_t)DOUT * K2 * 2;     // 2.16 MB
  unsigned short* A1T  = (unsigned short*)w;  w += (size_t)64 * DIN * 2;
  unsigned short* A2T  = (unsigned short*)w;  w += (size_t)64 * DHID * 2;

  // --- weight preprocessing: 1 launch ---
  prep_kernel<<<2848, 256, 0, stream>>>(W1, B1, W2, B2, W1cT, W2cT, A1, A2, A1T, A2T);
  // --- fused x-convert + u1 -> xaug[:,0:512] and [:,512:576] ---
  u1cvt_kernel<<<NR / 64, 256, 0, stream>>>(x, bw, A1T, xaug);
  // --- h = gelu(xaug @ [W1;B1cat] + b1) -> haug[:, 0:2048]  (R9-proven 256x256) ---
  gemmx_kernel<256, 256, 8, K1, 0><<<dim3(NR / 256, DHID / 256), 512, 0, stream>>>(
      xaug, K1, W1cT, K1, b1, haug, K2, 0);
  // --- u2 = 2*bw ⊙ (h @ A2cat) -> haug[:, 2048:2112] ---
  gemmu_kernel<64, 64, 32, 32, 2048><<<dim3(NR / 64, 1), 256, 0, stream>>>(
      haug, K2, A2T, DHID, bw, haug, K2, 2048);
  // --- out = haug @ [W2;B2cat] + b2 (fp32)
  //     (128x256, 8 waves, grid 256 = 1/CU; halves haug re-read 276->138 MB) ---
  gemmx_kernel<128, 256, 8, K2, 1><<<dim3(NR / 128, DOUT / 256), 512, 0, stream>>>(
      haug, K2, W2cT, K2, b2, out, DOUT, 0);
}

// Round 13
// 137.992 us; speedup vs baseline: 1.3619x; 1.0107x over previous
//
#include <hip/hip_runtime.h>
#include <hip/hip_bf16.h>

#define DEV __device__ __forceinline__
#define AS1 __attribute__((address_space(1)))
#define AS3 __attribute__((address_space(3)))

typedef __attribute__((ext_vector_type(8))) short bf16x8;
typedef __attribute__((ext_vector_type(4))) float f32x4;

static constexpr int NR   = 16384;
static constexpr int DIN  = 512;
static constexpr int DHID = 2048;
static constexpr int DOUT = 512;
static constexpr int LR   = 64;          // 4 bands * rank 16
static constexpr int K1   = DIN + LR;    // 576
static constexpr int K2   = DHID + LR;   // 2112

DEV unsigned short f2bf(float f) {
  unsigned u = __float_as_uint(f);
  u += 0x7fffu + ((u >> 16) & 1u);
  return (unsigned short)(u >> 16);
}

// fast GELU: tanh-form, |err vs erf-form| < ~1.5e-3 (well under bf16 quantum of h)
DEV float fast_gelu(float v) {
  float x2 = v * v;
  float a  = -v * __builtin_fmaf(0.10294324f, x2, 2.30220817f);
  float t  = exp2f(a);
  return v * __builtin_amdgcn_rcpf(1.0f + t);
}

template<int N> DEV void wvm() {
  asm volatile("s_waitcnt vmcnt(%0)" :: "i"(N) : "memory");
}

// ==================== fused weight preprocessing (1 launch) ====================
DEV void tconv_dev(const float* in, unsigned short* out, int C, int LDO, int CO,
                   int bx, int by, float (*t)[33], int tid) {
  int bc = bx * 32, br = by * 32;
  int tx = tid & 31, ty = tid >> 5;
  #pragma unroll
  for (int i = 0; i < 32; i += 8)
    t[ty + i][tx] = in[(size_t)(br + ty + i) * C + bc + tx];
  __syncthreads();
  #pragma unroll
  for (int i = 0; i < 32; i += 8)
    out[(size_t)(bc + ty + i) * LDO + CO + br + tx] = f2bf(t[tx][ty + i]);
}

__global__ __launch_bounds__(256) void prep_kernel(
    const float* __restrict__ W1, const float* __restrict__ B1,
    const float* __restrict__ W2, const float* __restrict__ B2,
    unsigned short* __restrict__ W1cT, unsigned short* __restrict__ W2cT,
    const float* __restrict__ A1, const float* __restrict__ A2,
    unsigned short* __restrict__ A1T, unsigned short* __restrict__ A2T) {
  __shared__ float t[32][33];
  const int b = blockIdx.x, tid = threadIdx.x;
  if (b < 1024) {                      // W1 [512][2048] -> W1cT [2048][576] @0
    tconv_dev(W1, W1cT, 2048, K1, 0, b & 63, b >> 6, t, tid);
  } else if (b < 2048) {               // W2 [2048][512] -> W2cT [512][2112] @0
    int bi = b - 1024;
    tconv_dev(W2, W2cT, 512, K2, 0, bi & 15, bi >> 4, t, tid);
  } else if (b < 2176) {               // B1cat [64][2048] -> W1cT cols @512
    int bi = b - 2048;
    tconv_dev(B1, W1cT, 2048, K1, 512, bi & 63, bi >> 6, t, tid);
  } else if (b < 2208) {               // B2cat [64][512] -> W2cT cols @2048
    int bi = b - 2176;
    tconv_dev(B2, W2cT, 512, K2, 2048, bi & 15, bi >> 4, t, tid);
  } else if (b < 2336) {               // A1 [4][512][16] -> A1T [64][512]
    int i2 = (b - 2208) * 256 + tid;
    int j = i2 / DIN, i = i2 - j * DIN;
    A1T[i2] = f2bf(A1[((size_t)(j >> 4) * DIN + i) * 16 + (j & 15)]);
  } else {                             // A2 [4][2048][16] -> A2T [64][2048]
    int i2 = (b - 2336) * 256 + tid;
    int j = i2 / DHID, i = i2 - j * DHID;
    A2T[i2] = f2bf(A2[((size_t)(j >> 4) * DHID + i) * 16 + (j & 15)]);
  }
}

// ========== fused cvt_x + u1: block = 64 rows, loops K=512 in 8 tiles ==========
__global__ __launch_bounds__(256) void u1cvt_kernel(
    const float* __restrict__ x, const float* __restrict__ bw,
    const unsigned short* __restrict__ A1T, unsigned short* __restrict__ xaug) {
  __shared__ __align__(16) unsigned short lX[64 * 64];
  __shared__ __align__(16) unsigned short lW[64 * 64];
  const int tid = threadIdx.x;
  const int w = tid >> 6, lane = tid & 63;
  const int bm = blockIdx.x * 64;
  const int l15 = lane & 15;
  const int kc0 = ((lane >> 4) ^ (lane & 7)) * 8;
  const int kc1 = (((lane >> 4) + 4) ^ (lane & 7)) * 8;

  f32x4 acc[4] = {};   // u1: 16 rows (this wave) x 4 n-frags of 16 cols

  for (int kt = 0; kt < 8; ++kt) {
    #pragma unroll
    for (int i = 0; i < 2; ++i) {
      int row = i * 32 + w * 8 + (lane >> 3);
      __builtin_amdgcn_global_load_lds(
          (const AS1 void*)(A1T + (size_t)row * DIN + kt * 64
                              + (((lane & 7) ^ (row & 7)) * 8)),
          (AS3 void*)(lW + (i * 32 + w * 8) * 64 + lane * 8), 16, 0, 0);
    }
    #pragma unroll
    for (int p = 0; p < 4; ++p) {
      int row = p * 16 + (tid >> 4);
      int col = (tid & 15) * 4;
      float4 v = *(const float4*)(x + (size_t)(bm + row) * DIN + kt * 64 + col);
      uint2 o;
      o.x = (unsigned)f2bf(v.x) | ((unsigned)f2bf(v.y) << 16);
      o.y = (unsigned)f2bf(v.z) | ((unsigned)f2bf(v.w) << 16);
      *(uint2*)(xaug + (size_t)(bm + row) * K1 + kt * 64 + col) = o;
      char* p3 = (char*)lX + row * 128 + (((col >> 3) ^ (row & 7)) << 4) + ((col & 7) << 1);
      *(uint2*)p3 = o;
    }
    __syncthreads();
    bf16x8 af0 = *(const bf16x8*)(lX + (w * 16 + l15) * 64 + kc0);
    bf16x8 af1 = *(const bf16x8*)(lX + (w * 16 + l15) * 64 + kc1);
    #pragma unroll
    for (int n = 0; n < 4; ++n) {
      bf16x8 b0 = *(const bf16x8*)(lW + (n * 16 + l15) * 64 + kc0);
      bf16x8 b1 = *(const bf16x8*)(lW + (n * 16 + l15) * 64 + kc1);
      acc[n] = __builtin_amdgcn_mfma_f32_16x16x32_bf16(af0, b0, acc[n], 0, 0, 0);
      acc[n] = __builtin_amdgcn_mfma_f32_16x16x32_bf16(af1, b1, acc[n], 0, 0, 0);
    }
    __syncthreads();
  }

  #pragma unroll
  for (int n = 0; n < 4; ++n) {
    int col = n * 16 + l15;
    #pragma unroll
    for (int r = 0; r < 4; ++r) {
      int row = bm + w * 16 + ((lane >> 4) << 2) + r;
      float v = acc[n][r] * 2.0f * bw[row * 4 + n];
      xaug[(size_t)row * K1 + 512 + col] = f2bf(v);
    }
  }
}

// ========== 2-barrier/tile double-buffered MFMA GEMM (R9 skeleton) + T1 XCD swizzle ==========
// 1-D grid; decode: t=bid>>3, by=t%NBY, bx=(t/NBY)*8 + (bid&7).
// All blocks sharing an A-panel (same bx) land on one XCD (assumes bid%8 round-robin;
// if mapping differs it's perf-only). Concurrent per-XCD working set ~3.5 MB <= 4 MB L2.
// setprio REMOVED (T5 measured negative on lockstep non-8-phase GEMM, m190).
// EPI: 0 = gelu(acc+bias)->bf16 out ; 1 = acc+bias->fp32 out
template<int BM, int BN, int WAVES, int K, int EPI, int NBY>
__global__ __launch_bounds__(WAVES * 64, 2) void gemmx_kernel(
    const unsigned short* __restrict__ A, int lda,
    const unsigned short* __restrict__ B, int ldb,
    const float* __restrict__ bias,
    void* __restrict__ outp, int ldo, int ocol) {
  constexpr int THREADS = WAVES * 64;
  constexpr int NT = K / 64;
  constexpr int AL = BM * 4 / THREADS;   // gload_lds/thread per A half (1|2)
  constexpr int BL = BN * 4 / THREADS;   // per B half
  constexpr int HA = (BM / 2) * 64;      // elems per half-slot
  constexpr int HB = (BN / 2) * 64;
  constexpr int MQ = BM / 64;            // m-frags per quadrant per wave
  constexpr int WC = WAVES / 2;
  static_assert(NT >= 2 && AL >= 1 && BL >= 1 && (BN / 2) / WC == 32, "geometry");
  __shared__ __align__(16) unsigned short lA[4 * HA];   // [buf][half]
  __shared__ __align__(16) unsigned short lB[4 * HB];

  const int tid  = threadIdx.x;
  const int w    = tid >> 6, lane = tid & 63;
  const int wr   = w / WC, wc = w % WC;
  // T1 XCD decode
  const int bid  = blockIdx.x;
  const int tt   = bid >> 3;
  const int by   = tt % NBY;
  const int bx   = (tt / NBY) * 8 + (bid & 7);
  const int bm   = bx * BM, bn = by * BN;
  const int l15  = lane & 15;
  const int kc0  = ((lane >> 4) ^ (lane & 7)) * 8;        // kk=0 chunk (swizzled)
  const int kc1  = (((lane >> 4) + 4) ^ (lane & 7)) * 8;  // kk=1 chunk

  f32x4 acc[2][2][MQ][2] = {};   // [mh][nh][m][n]
  bf16x8 af[2][MQ][2];           // [mh][m][kk] -- BOTH A halves resident
  bf16x8 bfv[2][2];              // [n][kk] -- current nh only

  auto stageA = [&](int buf, int half, int t) {
    #pragma unroll
    for (int i = 0; i < AL; ++i) {
      int row = w * (AL * 8) + i * 8 + (lane >> 3);
      __builtin_amdgcn_global_load_lds(
          (const AS1 void*)(A + (size_t)(bm + half * (BM / 2) + row) * lda
                              + (size_t)t * 64 + (((lane & 7) ^ (row & 7)) * 8)),
          (AS3 void*)(lA + (buf * 2 + half) * HA + (w * AL + i) * 512),
          16, 0, 0);
    }
  };
  auto stageB = [&](int buf, int half, int t) {
    #pragma unroll
    for (int i = 0; i < BL; ++i) {
      int row = w * (BL * 8) + i * 8 + (lane >> 3);
      __builtin_amdgcn_global_load_lds(
          (const AS1 void*)(B + (size_t)(bn + half * (BN / 2) + row) * ldb
                              + (size_t)t * 64 + (((lane & 7) ^ (row & 7)) * 8)),
          (AS3 void*)(lB + (buf * 2 + half) * HB + (w * BL + i) * 512),
          16, 0, 0);
    }
  };
  auto ldAall = [&](int buf) {
    #pragma unroll
    for (int mh = 0; mh < 2; ++mh) {
      const unsigned short* sA = lA + (buf * 2 + mh) * HA;
      #pragma unroll
      for (int m = 0; m < MQ; ++m) {
        int ro = (wr * (BM / 4) + m * 16 + l15) * 64;
        af[mh][m][0] = *(const bf16x8*)(sA + ro + kc0);
        af[mh][m][1] = *(const bf16x8*)(sA + ro + kc1);
      }
    }
  };
  auto ldB = [&](int buf, int nh) {
    const unsigned short* sB = lB + (buf * 2 + nh) * HB;
    #pragma unroll
    for (int n = 0; n < 2; ++n) {
      int ro = (wc * 32 + n * 16 + l15) * 64;
      bfv[n][0] = *(const bf16x8*)(sB + ro + kc0);
      bfv[n][1] = *(const bf16x8*)(sB + ro + kc1);
    }
  };

#define MFMA_Q(mh, nh)                                                           \
  _Pragma("unroll")                                                              \
  for (int m = 0; m < MQ; ++m)                                                   \
    _Pragma("unroll")                                                            \
    for (int n = 0; n < 2; ++n) {                                                \
      acc[mh][nh][m][n] = __builtin_amdgcn_mfma_f32_16x16x32_bf16(               \
          af[mh][m][0], bfv[n][0], acc[mh][nh][m][n], 0, 0, 0);                  \
      acc[mh][nh][m][n] = __builtin_amdgcn_mfma_f32_16x16x32_bf16(               \
          af[mh][m][1], bfv[n][1], acc[mh][nh][m][n], 0, 0, 0);                  \
    }

#define BAR() __builtin_amdgcn_s_barrier()

  // prologue: stage tile0 (A0,A1,B0,B1); land A0,A1,B0; keep B1 in flight
  stageA(0, 0, 0); stageA(0, 1, 0); stageB(0, 0, 0); stageB(0, 1, 0);
  wvm<BL>();
  BAR();

  for (int t = 0; t < NT; ++t) {
    const int buf = t & 1, nb = buf ^ 1;
    const bool more = (t + 1 < NT);
    ldAall(buf);
    ldB(buf, 0);
    if (more) { stageA(nb, 0, t + 1); stageA(nb, 1, t + 1); stageB(nb, 0, t + 1); }
    MFMA_Q(0, 0);
    MFMA_Q(1, 0);
    if (more) wvm<2 * AL + BL>(); else wvm<0>();   // B1(t) landed
    BAR();                                          // B1(t) visible to all waves
    if (more) stageB(nb, 1, t + 1);
    ldB(buf, 1);
    MFMA_Q(0, 1);
    MFMA_Q(1, 1);
    if (more) {
      wvm<BL>();                                    // A0,A1,B0(t+1) landed
      BAR();
    }
  }
#undef MFMA_Q
#undef BAR

  // epilogue: C/D layout col=lane&15, row=(lane>>4)*4+reg
  float biasv[2][2];
  #pragma unroll
  for (int nh = 0; nh < 2; ++nh)
    #pragma unroll
    for (int n = 0; n < 2; ++n)
      biasv[nh][n] = bias[bn + nh * (BN / 2) + wc * 32 + n * 16 + l15];

  #pragma unroll
  for (int mh = 0; mh < 2; ++mh)
    #pragma unroll
    for (int nh = 0; nh < 2; ++nh)
      #pragma unroll
      for (int m = 0; m < MQ; ++m)
        #pragma unroll
        for (int n = 0; n < 2; ++n) {
          int col  = bn + nh * (BN / 2) + wc * 32 + n * 16 + l15;
          int rowb = bm + mh * (BM / 2) + wr * (BM / 4) + m * 16 + ((lane >> 4) << 2);
          #pragma unroll
          for (int r = 0; r < 4; ++r) {
            float v = acc[mh][nh][m][n][r];
            int row = rowb + r;
            if (EPI == 0) {
              v = fast_gelu(v + biasv[nh][n]);
              ((unsigned short*)outp)[(size_t)row * ldo + ocol + col] = f2bf(v);
            } else {
              v += biasv[nh][n];
              ((float*)outp)[(size_t)row * ldo + col] = v;
            }
          }
        }
}

// ============ small GEMM for LoRA u2 projection: BK=64, 3-buffer counted ring ============
// EPI2: acc*2*bw[row][col>>4] -> bf16 out at col offset
template<int BM, int BN, int WM, int WN, int K>
__global__ __launch_bounds__(256) void gemmu_kernel(
    const unsigned short* __restrict__ A, int lda,
    const unsigned short* __restrict__ B, int ldb,
    const float* __restrict__ bw,
    unsigned short* __restrict__ outp, int ldo, int ocol) {
  constexpr int WRM = WM / 16, WRN = WN / 16;
  constexpr int NWN = BN / WN;
  constexpr int NT  = K / 64;
  constexpr int NBUF = 3;
  constexpr int AISS = BM * 64 * 2 / 4096;
  constexpr int BISS = BN * 64 * 2 / 4096;
  constexpr int LOADS = AISS + BISS;
  static_assert((BM / WM) * (BN / WN) == 4 && NT >= NBUF, "geometry");
  __shared__ __align__(16) unsigned short lA[NBUF * BM * 64];
  __shared__ __align__(16) unsigned short lB[NBUF * BN * 64];

  const int tid  = threadIdx.x;
  const int wid  = tid >> 6, lane = tid & 63;
  const int wr   = wid / NWN, wc = wid % NWN;
  const int bm   = blockIdx.x * BM, bn = blockIdx.y * BN;
  const int l15  = lane & 15;
  const int kc0  = ((lane >> 4) ^ (lane & 7)) * 8;
  const int kc1  = (((lane >> 4) + 4) ^ (lane & 7)) * 8;

  f32x4 acc[WRM][WRN] = {};

  auto stage = [&](int buf, int t) {
    #pragma unroll
    for (int i = 0; i < AISS; i++) {
      int row = (wid * AISS + i) * 8 + (lane >> 3);
      __builtin_amdgcn_global_load_lds(
          (const AS1 void*)(A + (size_t)(bm + row) * lda + (size_t)t * 64
                              + (((lane & 7) ^ (row & 7)) * 8)),
          (AS3 void*)(lA + buf * (BM * 64) + (wid * AISS + i) * 512), 16, 0, 0);
    }
    #pragma unroll
    for (int i = 0; i < BISS; i++) {
      int row = (wid * BISS + i) * 8 + (lane >> 3);
      __builtin_amdgcn_global_load_lds(
          (const AS1 void*)(B + (size_t)(bn + row) * ldb + (size_t)t * 64
                              + (((lane & 7) ^ (row & 7)) * 8)),
          (AS3 void*)(lB + buf * (BN * 64) + (wid * BISS + i) * 512), 16, 0, 0);
    }
  };
  auto compute = [&](int buf) {
    const unsigned short* pA = lA + buf * (BM * 64);
    const unsigned short* pB = lB + buf * (BN * 64);
    bf16x8 af[WRM][2], bfv[WRN][2];
    #pragma unroll
    for (int m = 0; m < WRM; m++) {
      int ro = (wr * WM + m * 16 + l15) * 64;
      af[m][0] = *(const bf16x8*)(pA + ro + kc0);
      af[m][1] = *(const bf16x8*)(pA + ro + kc1);
    }
    #pragma unroll
    for (int n = 0; n < WRN; n++) {
      int ro = (wc * WN + n * 16 + l15) * 64;
      bfv[n][0] = *(const bf16x8*)(pB + ro + kc0);
      bfv[n][1] = *(const bf16x8*)(pB + ro + kc1);
    }
    #pragma unroll
    for (int m = 0; m < WRM; m++)
      #pragma unroll
      for (int n = 0; n < WRN; n++) {
        acc[m][n] = __builtin_amdgcn_mfma_f32_16x16x32_bf16(af[m][0], bfv[n][0], acc[m][n], 0, 0, 0);
        acc[m][n] = __builtin_amdgcn_mfma_f32_16x16x32_bf16(af[m][1], bfv[n][1], acc[m][n], 0, 0, 0);
      }
  };

  stage(0, 0); stage(1, 1); stage(2, 2);
  wvm<2 * LOADS>();
  __builtin_amdgcn_s_barrier();

  int bt = 0;
  for (int t = 0; t < NT; ++t) {
    compute(bt);
    __builtin_amdgcn_s_barrier();
    if (t + 1 < NT) {
      if (t + NBUF < NT) stage(bt, t + NBUF);
      int newer = (t + NBUF < NT) ? (NBUF - 1) : (NT - 2 - t);
      if (newer >= 2)      wvm<2 * LOADS>();
      else if (newer == 1) wvm<LOADS>();
      else                 wvm<0>();
      __builtin_amdgcn_s_barrier();
      bt = (bt == NBUF - 1) ? 0 : bt + 1;
    }
  }

  const int r0 = bm + wr * WM;
  const int c0 = bn + wc * WN;
  #pragma unroll
  for (int m = 0; m < WRM; m++)
    #pragma unroll
    for (int n = 0; n < WRN; n++) {
      int col  = c0 + n * 16 + l15;
      int rowb = r0 + m * 16 + ((lane >> 4) << 2);
      #pragma unroll
      for (int r = 0; r < 4; r++) {
        float v = acc[m][n][r] * 2.0f * bw[(rowb + r) * 4 + (col >> 4)];
        outp[(size_t)(rowb + r) * ldo + ocol + col] = f2bf(v);
      }
    }
}

extern "C" void kernel_launch(void* const* d_in, const int* in_sizes, int n_in,
                              void* d_out, int out_size, void* d_ws, size_t ws_size,
                              hipStream_t stream) {
  const float* x  = (const float*)d_in[0];
  const float* bw = (const float*)d_in[1];
  const float* W1 = (const float*)d_in[2];
  const float* b1 = (const float*)d_in[3];
  const float* W2 = (const float*)d_in[4];
  const float* b2 = (const float*)d_in[5];
  const float* A1 = (const float*)d_in[6];
  const float* B1 = (const float*)d_in[7];
  const float* A2 = (const float*)d_in[8];
  const float* B2 = (const float*)d_in[9];
  float* out = (float*)d_out;

  char* w = (char*)d_ws;
  unsigned short* xaug = (unsigned short*)w;  w += (size_t)NR * K1 * 2;       // 18.9 MB
  unsigned short* haug = (unsigned short*)w;  w += (size_t)NR * K2 * 2;       // 69.2 MB
  unsigned short* W1cT = (unsigned short*)w;  w += (size_t)DHID * K1 * 2;     // 2.36 MB
  unsigned short* W2cT = (unsigned short*)w;  w += (size_t)DOUT * K2 * 2;     // 2.16 MB
  unsigned short* A1T  = (unsigned short*)w;  w += (size_t)64 * DIN * 2;
  unsigned short* A2T  = (unsigned short*)w;  w += (size_t)64 * DHID * 2;

  // --- weight preprocessing: 1 launch ---
  prep_kernel<<<2848, 256, 0, stream>>>(W1, B1, W2, B2, W1cT, W2cT, A1, A2, A1T, A2T);
  // --- fused x-convert + u1 -> xaug[:,0:512] and [:,512:576] ---
  u1cvt_kernel<<<NR / 64, 256, 0, stream>>>(x, bw, A1T, xaug);
  // --- h = gelu(xaug @ [W1;B1cat] + b1) -> haug[:, 0:2048]
  //     (256x256, 8 waves, T1 XCD swizzle: NBY=8, grid 512 1-D) ---
  gemmx_kernel<256, 256, 8, K1, 0, 8><<<dim3(512), 512, 0, stream>>>(
      xaug, K1, W1cT, K1, b1, haug, K2, 0);
  // --- u2 = 2*bw ⊙ (h @ A2cat) -> haug[:, 2048:2112] ---
  gemmu_kernel<64, 64, 32, 32, 2048><<<dim3(NR / 64, 1), 256, 0, stream>>>(
      haug, K2, A2T, DHID, bw, haug, K2, 2048);
  // --- out = haug @ [W2;B2cat] + b2 (fp32)
  //     (128x256, 8 waves, T1 XCD swizzle: NBY=2, grid 256 1-D) ---
  gemmx_kernel<128, 256, 8, K2, 1, 2><<<dim3(256), 512, 0, stream>>>(
      haug, K2, W2cT, K2, b2, out, DOUT, 0);
}

// Round 14
// 119.873 us; speedup vs baseline: 1.5677x; 1.1511x over previous
//
#include <hip/hip_runtime.h>
#include <hip/hip_bf16.h>

#define DEV __device__ __forceinline__
#define AS1 __attribute__((address_space(1)))
#define AS3 __attribute__((address_space(3)))

typedef __attribute__((ext_vector_type(8))) short bf16x8;
typedef __attribute__((ext_vector_type(4))) float f32x4;

static constexpr int NR   = 16384;
static constexpr int DIN  = 512;
static constexpr int DHID = 2048;
static constexpr int DOUT = 512;
static constexpr int LR   = 64;          // 4 bands * rank 16
static constexpr int K1   = DIN + LR;    // 576
static constexpr int K2   = DHID + LR;   // 2112

DEV unsigned short f2bf(float f) {
  unsigned u = __float_as_uint(f);
  u += 0x7fffu + ((u >> 16) & 1u);
  return (unsigned short)(u >> 16);
}

// fast GELU: tanh-form, |err vs erf-form| < ~1.5e-3 (well under bf16 quantum of h)
DEV float fast_gelu(float v) {
  float x2 = v * v;
  float a  = -v * __builtin_fmaf(0.10294324f, x2, 2.30220817f);
  float t  = exp2f(a);
  return v * __builtin_amdgcn_rcpf(1.0f + t);
}

template<int N> DEV void wvm() {
  asm volatile("s_waitcnt vmcnt(%0)" :: "i"(N) : "memory");
}
DEV void wlgkm0() { asm volatile("s_waitcnt lgkmcnt(0)" ::: "memory"); }

// ==================== fused weight preprocessing (1 launch) ====================
DEV void tconv_dev(const float* in, unsigned short* out, int C, int LDO, int CO,
                   int bx, int by, float (*t)[33], int tid) {
  int bc = bx * 32, br = by * 32;
  int tx = tid & 31, ty = tid >> 5;
  #pragma unroll
  for (int i = 0; i < 32; i += 8)
    t[ty + i][tx] = in[(size_t)(br + ty + i) * C + bc + tx];
  __syncthreads();
  #pragma unroll
  for (int i = 0; i < 32; i += 8)
    out[(size_t)(bc + ty + i) * LDO + CO + br + tx] = f2bf(t[tx][ty + i]);
}

__global__ __launch_bounds__(256) void prep_kernel(
    const float* __restrict__ W1, const float* __restrict__ B1,
    const float* __restrict__ W2, const float* __restrict__ B2,
    unsigned short* __restrict__ W1cT, unsigned short* __restrict__ W2cT,
    const float* __restrict__ A1, const float* __restrict__ A2,
    unsigned short* __restrict__ A1T, unsigned short* __restrict__ A2T) {
  __shared__ float t[32][33];
  const int b = blockIdx.x, tid = threadIdx.x;
  if (b < 1024) {                      // W1 [512][2048] -> W1cT [2048][576] @0
    tconv_dev(W1, W1cT, 2048, K1, 0, b & 63, b >> 6, t, tid);
  } else if (b < 2048) {               // W2 [2048][512] -> W2cT [512][2112] @0
    int bi = b - 1024;
    tconv_dev(W2, W2cT, 512, K2, 0, bi & 15, bi >> 4, t, tid);
  } else if (b < 2176) {               // B1cat [64][2048] -> W1cT cols @512
    int bi = b - 2048;
    tconv_dev(B1, W1cT, 2048, K1, 512, bi & 63, bi >> 6, t, tid);
  } else if (b < 2208) {               // B2cat [64][512] -> W2cT cols @2048
    int bi = b - 2176;
    tconv_dev(B2, W2cT, 512, K2, 2048, bi & 15, bi >> 4, t, tid);
  } else if (b < 2336) {               // A1 [4][512][16] -> A1T [64][512]
    int i2 = (b - 2208) * 256 + tid;
    int j = i2 / DIN, i = i2 - j * DIN;
    A1T[i2] = f2bf(A1[((size_t)(j >> 4) * DIN + i) * 16 + (j & 15)]);
  } else {                             // A2 [4][2048][16] -> A2T [64][2048]
    int i2 = (b - 2336) * 256 + tid;
    int j = i2 / DHID, i = i2 - j * DHID;
    A2T[i2] = f2bf(A2[((size_t)(j >> 4) * DHID + i) * 16 + (j & 15)]);
  }
}

// ========== fused cvt_x + u1: block = 64 rows, loops K=512 in 8 tiles ==========
__global__ __launch_bounds__(256) void u1cvt_kernel(
    const float* __restrict__ x, const float* __restrict__ bw,
    const unsigned short* __restrict__ A1T, unsigned short* __restrict__ xaug) {
  __shared__ __align__(16) unsigned short lX[64 * 64];
  __shared__ __align__(16) unsigned short lW[64 * 64];
  const int tid = threadIdx.x;
  const int w = tid >> 6, lane = tid & 63;
  const int bm = blockIdx.x * 64;
  const int l15 = lane & 15;
  const int kc0 = ((lane >> 4) ^ (lane & 7)) * 8;
  const int kc1 = (((lane >> 4) + 4) ^ (lane & 7)) * 8;

  f32x4 acc[4] = {};   // u1: 16 rows (this wave) x 4 n-frags of 16 cols

  for (int kt = 0; kt < 8; ++kt) {
    #pragma unroll
    for (int i = 0; i < 2; ++i) {
      int row = i * 32 + w * 8 + (lane >> 3);
      __builtin_amdgcn_global_load_lds(
          (const AS1 void*)(A1T + (size_t)row * DIN + kt * 64
                              + (((lane & 7) ^ (row & 7)) * 8)),
          (AS3 void*)(lW + (i * 32 + w * 8) * 64 + lane * 8), 16, 0, 0);
    }
    #pragma unroll
    for (int p = 0; p < 4; ++p) {
      int row = p * 16 + (tid >> 4);
      int col = (tid & 15) * 4;
      float4 v = *(const float4*)(x + (size_t)(bm + row) * DIN + kt * 64 + col);
      uint2 o;
      o.x = (unsigned)f2bf(v.x) | ((unsigned)f2bf(v.y) << 16);
      o.y = (unsigned)f2bf(v.z) | ((unsigned)f2bf(v.w) << 16);
      *(uint2*)(xaug + (size_t)(bm + row) * K1 + kt * 64 + col) = o;
      char* p3 = (char*)lX + row * 128 + (((col >> 3) ^ (row & 7)) << 4) + ((col & 7) << 1);
      *(uint2*)p3 = o;
    }
    __syncthreads();
    bf16x8 af0 = *(const bf16x8*)(lX + (w * 16 + l15) * 64 + kc0);
    bf16x8 af1 = *(const bf16x8*)(lX + (w * 16 + l15) * 64 + kc1);
    #pragma unroll
    for (int n = 0; n < 4; ++n) {
      bf16x8 b0 = *(const bf16x8*)(lW + (n * 16 + l15) * 64 + kc0);
      bf16x8 b1 = *(const bf16x8*)(lW + (n * 16 + l15) * 64 + kc1);
      acc[n] = __builtin_amdgcn_mfma_f32_16x16x32_bf16(af0, b0, acc[n], 0, 0, 0);
      acc[n] = __builtin_amdgcn_mfma_f32_16x16x32_bf16(af1, b1, acc[n], 0, 0, 0);
    }
    __syncthreads();
  }

  #pragma unroll
  for (int n = 0; n < 4; ++n) {
    int col = n * 16 + l15;
    #pragma unroll
    for (int r = 0; r < 4; ++r) {
      int row = bm + w * 16 + ((lane >> 4) << 2) + r;
      float v = acc[n][r] * 2.0f * bw[row * 4 + n];
      xaug[(size_t)row * K1 + 512 + col] = f2bf(v);
    }
  }
}

// ========== GEMM1: 2-barrier/tile dbuf (R9 skeleton) + T1 XCD swizzle (R13-proven) ==========
template<int BM, int BN, int WAVES, int K, int NBY>
__global__ __launch_bounds__(WAVES * 64, 2) void gemmx_kernel(
    const unsigned short* __restrict__ A, int lda,
    const unsigned short* __restrict__ B, int ldb,
    const float* __restrict__ bias,
    unsigned short* __restrict__ outp, int ldo) {
  constexpr int THREADS = WAVES * 64;
  constexpr int NT = K / 64;
  constexpr int AL = BM * 4 / THREADS;
  constexpr int BL = BN * 4 / THREADS;
  constexpr int HA = (BM / 2) * 64;
  constexpr int HB = (BN / 2) * 64;
  constexpr int MQ = BM / 64;
  constexpr int WC = WAVES / 2;
  static_assert(NT >= 2 && AL >= 1 && BL >= 1 && (BN / 2) / WC == 32, "geometry");
  __shared__ __align__(16) unsigned short lA[4 * HA];
  __shared__ __align__(16) unsigned short lB[4 * HB];

  const int tid  = threadIdx.x;
  const int w    = tid >> 6, lane = tid & 63;
  const int wr   = w / WC, wc = w % WC;
  const int bid  = blockIdx.x;
  const int tt   = bid >> 3;
  const int by   = tt % NBY;
  const int bx   = (tt / NBY) * 8 + (bid & 7);
  const int bm   = bx * BM, bn = by * BN;
  const int l15  = lane & 15;
  const int kc0  = ((lane >> 4) ^ (lane & 7)) * 8;
  const int kc1  = (((lane >> 4) + 4) ^ (lane & 7)) * 8;

  f32x4 acc[2][2][MQ][2] = {};
  bf16x8 af[2][MQ][2];
  bf16x8 bfv[2][2];

  auto stageA = [&](int buf, int half, int t) {
    #pragma unroll
    for (int i = 0; i < AL; ++i) {
      int row = w * (AL * 8) + i * 8 + (lane >> 3);
      __builtin_amdgcn_global_load_lds(
          (const AS1 void*)(A + (size_t)(bm + half * (BM / 2) + row) * lda
                              + (size_t)t * 64 + (((lane & 7) ^ (row & 7)) * 8)),
          (AS3 void*)(lA + (buf * 2 + half) * HA + (w * AL + i) * 512),
          16, 0, 0);
    }
  };
  auto stageB = [&](int buf, int half, int t) {
    #pragma unroll
    for (int i = 0; i < BL; ++i) {
      int row = w * (BL * 8) + i * 8 + (lane >> 3);
      __builtin_amdgcn_global_load_lds(
          (const AS1 void*)(B + (size_t)(bn + half * (BN / 2) + row) * ldb
                              + (size_t)t * 64 + (((lane & 7) ^ (row & 7)) * 8)),
          (AS3 void*)(lB + (buf * 2 + half) * HB + (w * BL + i) * 512),
          16, 0, 0);
    }
  };
  auto ldAall = [&](int buf) {
    #pragma unroll
    for (int mh = 0; mh < 2; ++mh) {
      const unsigned short* sA = lA + (buf * 2 + mh) * HA;
      #pragma unroll
      for (int m = 0; m < MQ; ++m) {
        int ro = (wr * (BM / 4) + m * 16 + l15) * 64;
        af[mh][m][0] = *(const bf16x8*)(sA + ro + kc0);
        af[mh][m][1] = *(const bf16x8*)(sA + ro + kc1);
      }
    }
  };
  auto ldB = [&](int buf, int nh) {
    const unsigned short* sB = lB + (buf * 2 + nh) * HB;
    #pragma unroll
    for (int n = 0; n < 2; ++n) {
      int ro = (wc * 32 + n * 16 + l15) * 64;
      bfv[n][0] = *(const bf16x8*)(sB + ro + kc0);
      bfv[n][1] = *(const bf16x8*)(sB + ro + kc1);
    }
  };

#define MFMA_Q(mh, nh)                                                           \
  _Pragma("unroll")                                                              \
  for (int m = 0; m < MQ; ++m)                                                   \
    _Pragma("unroll")                                                            \
    for (int n = 0; n < 2; ++n) {                                                \
      acc[mh][nh][m][n] = __builtin_amdgcn_mfma_f32_16x16x32_bf16(               \
          af[mh][m][0], bfv[n][0], acc[mh][nh][m][n], 0, 0, 0);                  \
      acc[mh][nh][m][n] = __builtin_amdgcn_mfma_f32_16x16x32_bf16(               \
          af[mh][m][1], bfv[n][1], acc[mh][nh][m][n], 0, 0, 0);                  \
    }

#define BAR() __builtin_amdgcn_s_barrier()

  stageA(0, 0, 0); stageA(0, 1, 0); stageB(0, 0, 0); stageB(0, 1, 0);
  wvm<BL>();
  BAR();

  for (int t = 0; t < NT; ++t) {
    const int buf = t & 1, nb = buf ^ 1;
    const bool more = (t + 1 < NT);
    ldAall(buf);
    ldB(buf, 0);
    if (more) { stageA(nb, 0, t + 1); stageA(nb, 1, t + 1); stageB(nb, 0, t + 1); }
    MFMA_Q(0, 0);
    MFMA_Q(1, 0);
    if (more) wvm<2 * AL + BL>(); else wvm<0>();
    BAR();
    if (more) stageB(nb, 1, t + 1);
    ldB(buf, 1);
    MFMA_Q(0, 1);
    MFMA_Q(1, 1);
    if (more) {
      wvm<BL>();
      BAR();
    }
  }
#undef MFMA_Q
#undef BAR

  float biasv[2][2];
  #pragma unroll
  for (int nh = 0; nh < 2; ++nh)
    #pragma unroll
    for (int n = 0; n < 2; ++n)
      biasv[nh][n] = bias[bn + nh * (BN / 2) + wc * 32 + n * 16 + l15];

  #pragma unroll
  for (int mh = 0; mh < 2; ++mh)
    #pragma unroll
    for (int nh = 0; nh < 2; ++nh)
      #pragma unroll
      for (int m = 0; m < MQ; ++m)
        #pragma unroll
        for (int n = 0; n < 2; ++n) {
          int col  = bn + nh * (BN / 2) + wc * 32 + n * 16 + l15;
          int rowb = bm + mh * (BM / 2) + wr * (BM / 4) + m * 16 + ((lane >> 4) << 2);
          #pragma unroll
          for (int r = 0; r < 4; ++r) {
            float v = fast_gelu(acc[mh][nh][m][n][r] + biasv[nh][n]);
            outp[(size_t)(rowb + r) * ldo + col] = f2bf(v);
          }
        }
}

// ========== GEMM2 with FUSED u2: per block, accumulate u2 = 2bw⊙(h@A2cat) during
// the 32 h-K-tiles (extra B-operand A2T, +1 load, +8 MFMA/tile), then exchange the
// bf16 u2 through the freed U-LDS slots and run the final K-tile (k=2048..2111)
// with the self-computed u2 as the A-operand. Eliminates the standalone u2 pass.
// Ledger (AL=1,BL=2,UL=1): entry [B1(t):2]; +5 early (A0,A1,B0,U of t+1) -> wvm<5>
// mid (B1(t) landed); +2 (B1(t+1)) -> wvm<2> end. t=31: +4 early (final B tile),
// wvm<4> mid; post-loop wvm<0> + lgkmcnt(0) + BAR for the u2 exchange.
template<int NBY>
__global__ __launch_bounds__(512, 2) void gemm2f_kernel(
    const unsigned short* __restrict__ A, int lda,        // haug [NR][K2]
    const unsigned short* __restrict__ B, int ldb,        // W2cT [512][K2]
    const unsigned short* __restrict__ U,                 // A2T  [64][2048]
    const float* __restrict__ bias, const float* __restrict__ bw,
    float* __restrict__ outp, int ldo) {
  constexpr int BM = 128, BN = 256;
  constexpr int NTH = DHID / 64;       // 32 h-tiles
  constexpr int AL = 1, BL = 2;
  constexpr int HA = (BM / 2) * 64;    // 4096
  constexpr int HB = (BN / 2) * 64;    // 8192
  constexpr int MQ = BM / 64;          // 2
  constexpr int WC = 4;
  __shared__ __align__(16) unsigned short lA[4 * HA];
  __shared__ __align__(16) unsigned short lB[4 * HB];
  __shared__ __align__(16) unsigned short lU[2 * 4096];   // U dbuf; reused as u2[128][64]

  const int tid  = threadIdx.x;
  const int w    = tid >> 6, lane = tid & 63;
  const int wr   = w / WC, wc = w % WC;
  const int bid  = blockIdx.x;
  const int tt   = bid >> 3;
  const int by   = tt % NBY;
  const int bx   = (tt / NBY) * 8 + (bid & 7);
  const int bm   = bx * BM, bn = by * BN;
  const int l15  = lane & 15;
  const int kc0  = ((lane >> 4) ^ (lane & 7)) * 8;
  const int kc1  = (((lane >> 4) + 4) ^ (lane & 7)) * 8;

  f32x4 acc[2][2][MQ][2] = {};   // main output
  f32x4 uacc[2][MQ] = {};        // u2 partial: [mh][m], cols = wc*16+l15
  bf16x8 af[2][MQ][2];
  bf16x8 bfv[2][2];
  bf16x8 bu[2];

  auto stageA = [&](int buf, int half, int t) {
    int row = w * 8 + (lane >> 3);
    __builtin_amdgcn_global_load_lds(
        (const AS1 void*)(A + (size_t)(bm + half * 64 + row) * lda
                            + (size_t)t * 64 + (((lane & 7) ^ (row & 7)) * 8)),
        (AS3 void*)(lA + (buf * 2 + half) * HA + w * 512),
        16, 0, 0);
  };
  auto stageB = [&](int buf, int half, int t) {
    #pragma unroll
    for (int i = 0; i < BL; ++i) {
      int row = w * 16 + i * 8 + (lane >> 3);
      __builtin_amdgcn_global_load_lds(
          (const AS1 void*)(B + (size_t)(bn + half * 128 + row) * ldb
                              + (size_t)t * 64 + (((lane & 7) ^ (row & 7)) * 8)),
          (AS3 void*)(lB + (buf * 2 + half) * HB + (w * BL + i) * 512),
          16, 0, 0);
    }
  };
  auto stageU = [&](int buf, int t) {
    int row = w * 8 + (lane >> 3);
    __builtin_amdgcn_global_load_lds(
        (const AS1 void*)(U + (size_t)row * DHID
                            + (size_t)t * 64 + (((lane & 7) ^ (row & 7)) * 8)),
        (AS3 void*)(lU + buf * 4096 + w * 512),
        16, 0, 0);
  };
  auto ldAall = [&](int buf) {
    #pragma unroll
    for (int mh = 0; mh < 2; ++mh) {
      const unsigned short* sA = lA + (buf * 2 + mh) * HA;
      #pragma unroll
      for (int m = 0; m < MQ; ++m) {
        int ro = (wr * 32 + m * 16 + l15) * 64;
        af[mh][m][0] = *(const bf16x8*)(sA + ro + kc0);
        af[mh][m][1] = *(const bf16x8*)(sA + ro + kc1);
      }
    }
  };
  auto ldB = [&](int buf, int nh) {
    const unsigned short* sB = lB + (buf * 2 + nh) * HB;
    #pragma unroll
    for (int n = 0; n < 2; ++n) {
      int ro = (wc * 32 + n * 16 + l15) * 64;
      bfv[n][0] = *(const bf16x8*)(sB + ro + kc0);
      bfv[n][1] = *(const bf16x8*)(sB + ro + kc1);
    }
  };
  auto ldU = [&](int buf) {
    const unsigned short* sU = lU + buf * 4096;
    int ro = (wc * 16 + l15) * 64;
    bu[0] = *(const bf16x8*)(sU + ro + kc0);
    bu[1] = *(const bf16x8*)(sU + ro + kc1);
  };

#define MFMA_Q(mh, nh)                                                           \
  _Pragma("unroll")                                                              \
  for (int m = 0; m < MQ; ++m)                                                   \
    _Pragma("unroll")                                                            \
    for (int n = 0; n < 2; ++n) {                                                \
      acc[mh][nh][m][n] = __builtin_amdgcn_mfma_f32_16x16x32_bf16(               \
          af[mh][m][0], bfv[n][0], acc[mh][nh][m][n], 0, 0, 0);                  \
      acc[mh][nh][m][n] = __builtin_amdgcn_mfma_f32_16x16x32_bf16(               \
          af[mh][m][1], bfv[n][1], acc[mh][nh][m][n], 0, 0, 0);                  \
    }

#define BAR() __builtin_amdgcn_s_barrier()

  // prologue: tile0 A0,A1,B0,U0 then B1; land all but B1
  stageA(0, 0, 0); stageA(0, 1, 0); stageB(0, 0, 0); stageU(0, 0); stageB(0, 1, 0);
  wvm<2>();
  BAR();

  for (int t = 0; t < NTH; ++t) {
    const int buf = t & 1, nb = buf ^ 1;
    const bool more = (t + 1 < NTH);
    ldAall(buf);
    ldB(buf, 0);
    ldU(buf);
    if (more) {
      stageA(nb, 0, t + 1); stageA(nb, 1, t + 1); stageB(nb, 0, t + 1); stageU(nb, t + 1);
    } else {
      stageB(nb, 0, NTH); stageB(nb, 1, NTH);   // final K-tile's B (k=2048..2111)
    }
    MFMA_Q(0, 0);
    MFMA_Q(1, 0);
    // u2 accumulation (af both halves resident)
    #pragma unroll
    for (int mh = 0; mh < 2; ++mh)
      #pragma unroll
      for (int m = 0; m < MQ; ++m) {
        uacc[mh][m] = __builtin_amdgcn_mfma_f32_16x16x32_bf16(af[mh][m][0], bu[0], uacc[mh][m], 0, 0, 0);
        uacc[mh][m] = __builtin_amdgcn_mfma_f32_16x16x32_bf16(af[mh][m][1], bu[1], uacc[mh][m], 0, 0, 0);
      }
    if (more) wvm<5>(); else wvm<4>();   // B1(t) landed
    BAR();
    if (more) stageB(nb, 1, t + 1);
    ldB(buf, 1);
    MFMA_Q(0, 1);
    MFMA_Q(1, 1);
    if (more) {
      wvm<2>();                          // A0,A1,B0,U(t+1) landed
      BAR();
    }
  }

  // ---- u2 exchange: scale, cvt, write into lU as [128][64] (std swizzle) ----
  #pragma unroll
  for (int mh = 0; mh < 2; ++mh)
    #pragma unroll
    for (int m = 0; m < MQ; ++m)
      #pragma unroll
      for (int r = 0; r < 4; ++r) {
        int row = mh * 64 + wr * 32 + m * 16 + ((lane >> 4) << 2) + r;
        float v = uacc[mh][m][r] * 2.0f * bw[(size_t)(bm + row) * 4 + wc];
        int kcol = wc * 16 + l15;
        *(unsigned short*)((char*)lU + row * 128
            + ((((kcol >> 3) ^ (row & 7))) << 4) + ((kcol & 7) << 1)) = f2bf(v);
      }
  wvm<0>();       // final B tile landed
  wlgkm0();       // u2 ds_writes complete
  BAR();          // u2 + final B visible to all waves

  // ---- final K-tile: A = u2 (from lU), B = staged final tile (buf 0... nb of t=31) ----
  {
    const int fbuf = (NTH - 1) & 1 ? 0 : 1;   // nb at t=NTH-1
    #pragma unroll
    for (int mh = 0; mh < 2; ++mh) {
      const unsigned short* sA = lU + mh * 4096;
      #pragma unroll
      for (int m = 0; m < MQ; ++m) {
        int ro = (wr * 32 + m * 16 + l15) * 64;
        af[mh][m][0] = *(const bf16x8*)(sA + ro + kc0);
        af[mh][m][1] = *(const bf16x8*)(sA + ro + kc1);
      }
    }
    ldB(fbuf, 0);
    MFMA_Q(0, 0);
    MFMA_Q(1, 0);
    ldB(fbuf, 1);
    MFMA_Q(0, 1);
    MFMA_Q(1, 1);
  }
#undef MFMA_Q
#undef BAR

  // ---- epilogue: bias + fp32 store ----
  float biasv[2][2];
  #pragma unroll
  for (int nh = 0; nh < 2; ++nh)
    #pragma unroll
    for (int n = 0; n < 2; ++n)
      biasv[nh][n] = bias[bn + nh * 128 + wc * 32 + n * 16 + l15];

  #pragma unroll
  for (int mh = 0; mh < 2; ++mh)
    #pragma unroll
    for (int nh = 0; nh < 2; ++nh)
      #pragma unroll
      for (int m = 0; m < MQ; ++m)
        #pragma unroll
        for (int n = 0; n < 2; ++n) {
          int col  = bn + nh * 128 + wc * 32 + n * 16 + l15;
          int rowb = bm + mh * 64 + wr * 32 + m * 16 + ((lane >> 4) << 2);
          #pragma unroll
          for (int r = 0; r < 4; ++r)
            outp[(size_t)(rowb + r) * ldo + col] = acc[mh][nh][m][n][r] + biasv[nh][n];
        }
}

extern "C" void kernel_launch(void* const* d_in, const int* in_sizes, int n_in,
                              void* d_out, int out_size, void* d_ws, size_t ws_size,
                              hipStream_t stream) {
  const float* x  = (const float*)d_in[0];
  const float* bw = (const float*)d_in[1];
  const float* W1 = (const float*)d_in[2];
  const float* b1 = (const float*)d_in[3];
  const float* W2 = (const float*)d_in[4];
  const float* b2 = (const float*)d_in[5];
  const float* A1 = (const float*)d_in[6];
  const float* B1 = (const float*)d_in[7];
  const float* A2 = (const float*)d_in[8];
  const float* B2 = (const float*)d_in[9];
  float* out = (float*)d_out;

  char* w = (char*)d_ws;
  unsigned short* xaug = (unsigned short*)w;  w += (size_t)NR * K1 * 2;       // 18.9 MB
  unsigned short* haug = (unsigned short*)w;  w += (size_t)NR * DHID * 2;     // 67.1 MB (h only)
  unsigned short* W1cT = (unsigned short*)w;  w += (size_t)DHID * K1 * 2;     // 2.36 MB
  unsigned short* W2cT = (unsigned short*)w;  w += (size_t)DOUT * K2 * 2;     // 2.16 MB
  unsigned short* A1T  = (unsigned short*)w;  w += (size_t)64 * DIN * 2;
  unsigned short* A2T  = (unsigned short*)w;  w += (size_t)64 * DHID * 2;

  // --- weight preprocessing: 1 launch ---
  prep_kernel<<<2848, 256, 0, stream>>>(W1, B1, W2, B2, W1cT, W2cT, A1, A2, A1T, A2T);
  // --- fused x-convert + u1 -> xaug[:,0:512] and [:,512:576] ---
  u1cvt_kernel<<<NR / 64, 256, 0, stream>>>(x, bw, A1T, xaug);
  // --- h = gelu(xaug @ [W1;B1cat] + b1) -> haug[:,0:2048] (stride 2048 now) ---
  gemmx_kernel<256, 256, 8, K1, 8><<<dim3(512), 512, 0, stream>>>(
      xaug, K1, W1cT, K1, b1, haug, DHID);
  // --- out = [h|u2] @ [W2;B2cat] + b2, u2 computed in-kernel (fused) ---
  gemm2f_kernel<2><<<dim3(256), 512, 0, stream>>>(
      haug, DHID, W2cT, K2, A2T, b2, bw, out, DOUT);
}